// Round 2
// baseline (296.322 us; speedup 1.0000x reference)
//
#include <hip/hip_runtime.h>
#include <hip/hip_bf16.h>

typedef short short8 __attribute__((ext_vector_type(8)));
typedef short short4v __attribute__((ext_vector_type(4)));
typedef float float4v __attribute__((ext_vector_type(4)));

#define B_   2
#define L_   1024
#define DIN  512
#define DM   1024
#define DS   16
#define DD   64
#define KER_ 4
#define NROW (B_*L_)     // 2048

// scan geometry: block = (b, 4 d-lanes); 128 chunks x 8 steps = L, 512 thr
#define SD   4
#define SC   128
#define SLC  8
#define NSEG 8           // phase-B segments (SC/16)

__device__ __forceinline__ float silu_f(float v){ return v / (1.f + expf(-v)); }

__device__ __forceinline__ short2 f2bf2(float a, float b) {
  __hip_bfloat162 h = __float22bfloat162_rn(float2{a, b});
  union { __hip_bfloat162 h; short2 s; } u; u.h = h; return u.s;
}
__device__ __forceinline__ short f2bf1(float a) {
  __hip_bfloat16 h = __float2bfloat16(a);
  union { __hip_bfloat16 h; short s; } u; u.h = h; return u.s;
}
__device__ __forceinline__ short8 pack8(const float4& x0, const float4& x1) {
  short2 s0 = f2bf2(x0.x, x0.y), s1 = f2bf2(x0.z, x0.w);
  short2 s2 = f2bf2(x1.x, x1.y), s3 = f2bf2(x1.z, x1.w);
  return short8{ s0.x, s0.y, s1.x, s1.y, s2.x, s2.y, s3.x, s3.y };
}
__device__ __forceinline__ float bf2f(short s) {
  union { unsigned u; float f; } v; v.u = ((unsigned)(unsigned short)s) << 16; return v.f;
}

// ---------------------------------------------------------------------------
// GEMM1: ab[2048,2048](bf16) = seq[2048,512] . Win[2048,512]^T
// BM=BN=64, 256 thr = 4 waves (2x2), wave tile 32x32, BK=32, reg-prefetch.
// Also zeroes pall (disjoint from own writes; stream order covers proj).
// ---------------------------------------------------------------------------
__global__ __launch_bounds__(256)
void gemm1_k(const float* __restrict__ seq, const float* __restrict__ Win,
             __hip_bfloat16* __restrict__ ab, float* __restrict__ pall) {
  __shared__ short As[64 * 40];
  __shared__ short Bs[64 * 40];
  const int tid  = threadIdx.x;
  // fold-in: zero pall (196608 floats over 1024 blocks x 256 thr)
  {
    int zi = (blockIdx.y * 32 + blockIdx.x) * 256 + tid;
    if (zi < NROW * 96) pall[zi] = 0.f;
  }
  const int lane = tid & 63;
  const int wave = tid >> 6;
  const int r16  = lane & 15;
  const int quad = lane >> 4;
  const int m0 = blockIdx.y * 64;
  const int n0 = blockIdx.x * 64;
  const int wm = wave & 1, wn = wave >> 1;
  float4v acc[2][2];
#pragma unroll
  for (int i = 0; i < 2; i++)
#pragma unroll
    for (int j = 0; j < 2; j++) acc[i][j] = (float4v){0.f, 0.f, 0.f, 0.f};
  float4 pf0[2], pf1[2];
  auto ldu = [&](int j, int k0) {
    int u = tid + j * 256;
    const float4* p;
    if (u < 256) { int row = u >> 2, q = u & 3;
      p = (const float4*)(seq + (size_t)(m0 + row) * DIN + k0 + q * 8);
    } else { int v = u - 256; int row = v >> 2, q = v & 3;
      p = (const float4*)(Win + (size_t)(n0 + row) * DIN + k0 + q * 8);
    }
    pf0[j] = p[0]; pf1[j] = p[1];
  };
  auto stu = [&](int j) {
    int u = tid + j * 256;
    short8 s = pack8(pf0[j], pf1[j]);
    if (u < 256) { int row = u >> 2, q = u & 3; *(short8*)&As[row * 40 + q * 8] = s; }
    else { int v = u - 256; int row = v >> 2, q = v & 3; *(short8*)&Bs[row * 40 + q * 8] = s; }
  };
  ldu(0, 0); ldu(1, 0);
  for (int k0 = 0; k0 < DIN; k0 += 32) {
    stu(0); stu(1);
    __syncthreads();
    if (k0 + 32 < DIN) { ldu(0, k0 + 32); ldu(1, k0 + 32); }
    short8 afr[2], bfr[2];
#pragma unroll
    for (int mi = 0; mi < 2; mi++)
      afr[mi] = *(const short8*)&As[(wm * 32 + mi * 16 + r16) * 40 + quad * 8];
#pragma unroll
    for (int ni = 0; ni < 2; ni++)
      bfr[ni] = *(const short8*)&Bs[(wn * 32 + ni * 16 + r16) * 40 + quad * 8];
#pragma unroll
    for (int mi = 0; mi < 2; mi++)
#pragma unroll
      for (int ni = 0; ni < 2; ni++)
        acc[mi][ni] = __builtin_amdgcn_mfma_f32_16x16x32_bf16(afr[mi], bfr[ni], acc[mi][ni], 0, 0, 0);
    __syncthreads();
  }
#pragma unroll
  for (int mi = 0; mi < 2; mi++)
#pragma unroll
    for (int ni = 0; ni < 2; ni++) {
      int gn = n0 + wn * 32 + ni * 16 + r16;
#pragma unroll
      for (int r = 0; r < 4; r++) {
        int gm = m0 + wm * 32 + mi * 16 + quad * 4 + r;
        ab[(size_t)gm * (2 * DM) + gn] = __float2bfloat16(acc[mi][ni][r]);
      }
    }
}

// ---------------------------------------------------------------------------
// convT + proj merged (independent consumers of ab; block-range split).
// blk < 1024: convT tile -> xT (f32, silu(conv)) / gT (bf16 gate transpose).
// blk >= 1024: proj split-K block -> pall atomicAdd (pall zeroed by gemm1).
// ---------------------------------------------------------------------------
__global__ __launch_bounds__(256)
void convproj_k(const __hip_bfloat16* __restrict__ ab, const float* __restrict__ cw,
                const float* __restrict__ cb, const float* __restrict__ WB,
                const float* __restrict__ WC, const float* __restrict__ WD1,
                float* __restrict__ xt, short* __restrict__ gt,
                float* __restrict__ pall) {
  __shared__ char smraw[12800];
  const int blk = blockIdx.x;
  const int tid = threadIdx.x;

  if (blk < 1024) {
    // ---------------- convT (verbatim R13 body) -------------------------
    short* tile = (short*)smraw;               // 67*74 shorts = 9916 B
    const int n0 = (blk & 31) * 64;
    const int d0 = (blk >> 5) * 64;            // 0..2047
    const int l0 = n0 & (L_ - 1);
    for (int u = tid; u < 67 * 8; u += 256) {
      int r = u >> 3, c8 = u & 7;
      int l = l0 - 3 + r;
      short8 v = short8{0, 0, 0, 0, 0, 0, 0, 0};
      if (l >= 0 && r < 67)
        v = *(const short8*)(ab + (size_t)(n0 - l0 + l) * (2 * DM) + d0 + c8 * 8);
      *(short8*)&tile[r * 74 + c8 * 8] = v;
    }
    __syncthreads();
    const int i  = tid & 63;
    const int dl = tid >> 6;                   // 0..3
    if (d0 < DM) {
#pragma unroll 4
      for (int p = 0; p < 16; p++) {
        int dc = p * 4 + dl;
        int d  = d0 + dc;
        float4 w = *(const float4*)(cw + d * 4);
        float a = cb[d];
        a += bf2f(tile[(i + 0) * 74 + dc]) * w.x;
        a += bf2f(tile[(i + 1) * 74 + dc]) * w.y;
        a += bf2f(tile[(i + 2) * 74 + dc]) * w.z;
        a += bf2f(tile[(i + 3) * 74 + dc]) * w.w;
        xt[(size_t)d * NROW + n0 + i] = silu_f(a);
      }
    } else {
#pragma unroll 4
      for (int p = 0; p < 16; p++) {
        int dc = p * 4 + dl;
        gt[(size_t)(d0 - DM + dc) * NROW + n0 + i] = tile[(i + 3) * 74 + dc];
      }
    }
    return;
  }

  // ---------------- proj (verbatim R13 body) ----------------------------
  short* As = (short*)smraw;                   // 64*40
  short* Bs = As + 64 * 40;                    // 96*40  (total 12800 B)
  const int b2   = blk - 1024;                 // 0..255
  const int lane = tid & 63;
  const int wave = tid >> 6;
  const int r16  = lane & 15;
  const int quad = lane >> 4;
  const int m0   = (b2 & 31) * 64;
  const int kbeg = (b2 >> 5) * 128;
  float4v acc[6];
#pragma unroll
  for (int i = 0; i < 6; i++) acc[i] = (float4v){0.f, 0.f, 0.f, 0.f};

  short8 ta[KER_];
  float4 pf0[2], pf1[2];
  const int arow = tid >> 2, aq = tid & 3;
  const int an = m0 + arow, al = an & (L_ - 1), abq = an >> 10;

  auto ldu_a = [&](int k0) {
#pragma unroll
    for (int t = 0; t < KER_; t++) {
      int ll = al - (KER_ - 1) + t;
      if (ll >= 0)
        ta[t] = *(const short8*)(ab + (size_t)(abq * L_ + ll) * (2 * DM) + k0 + aq * 8);
      else
        ta[t] = short8{0, 0, 0, 0, 0, 0, 0, 0};
    }
  };
  auto stu_a = [&](int k0) {
    float r8[8];
#pragma unroll
    for (int e = 0; e < 8; e++) {
      int d = k0 + aq * 8 + e;
      float4 w = *(const float4*)(cw + d * 4);
      float a = cb[d];
      a += bf2f(ta[0][e]) * w.x;
      a += bf2f(ta[1][e]) * w.y;
      a += bf2f(ta[2][e]) * w.z;
      a += bf2f(ta[3][e]) * w.w;
      r8[e] = silu_f(a);
    }
    *(short8*)&As[arow * 40 + aq * 8] =
        pack8(float4{r8[0], r8[1], r8[2], r8[3]}, float4{r8[4], r8[5], r8[6], r8[7]});
  };
  auto ldu_b = [&](int j, int k0) {
    int u = tid + j * 256;
    if (u >= 640) return;
    int v = u - 256, row = v >> 2, q = v & 3;
    const float* bp = (row < 16) ? (WB + (size_t)row * DM)
                    : (row < 32) ? (WC + (size_t)(row - 16) * DM)
                                 : (WD1 + (size_t)(row - 32) * DM);
    const float4* p = (const float4*)(bp + k0 + q * 8);
    pf0[j - 1] = p[0]; pf1[j - 1] = p[1];
  };
  auto stu_b = [&](int j) {
    int u = tid + j * 256;
    if (u >= 640) return;
    int v = u - 256, row = v >> 2, q = v & 3;
    *(short8*)&Bs[row * 40 + q * 8] = pack8(pf0[j - 1], pf1[j - 1]);
  };

  ldu_a(kbeg); ldu_b(1, kbeg); ldu_b(2, kbeg);
  for (int k0 = kbeg; k0 < kbeg + 128; k0 += 32) {
    stu_a(k0); stu_b(1); stu_b(2);
    __syncthreads();
    if (k0 + 32 < kbeg + 128) { ldu_a(k0 + 32); ldu_b(1, k0 + 32); ldu_b(2, k0 + 32); }
    short8 afr = *(const short8*)&As[(wave * 16 + r16) * 40 + quad * 8];
#pragma unroll
    for (int ni = 0; ni < 6; ni++) {
      short8 bfr = *(const short8*)&Bs[(ni * 16 + r16) * 40 + quad * 8];
      acc[ni] = __builtin_amdgcn_mfma_f32_16x16x32_bf16(afr, bfr, acc[ni], 0, 0, 0);
    }
    __syncthreads();
  }
#pragma unroll
  for (int ni = 0; ni < 6; ni++) {
    int gn = ni * 16 + r16;
#pragma unroll
    for (int r = 0; r < 4; r++) {
      int gm = m0 + wave * 16 + quad * 4 + r;
      atomicAdd(&pall[(size_t)gm * 96 + gn], acc[ni][r]);
    }
  }
}

// ---------------------------------------------------------------------------
// Fused selective scan. R15: delta_k eliminated — each thread computes its 8
// deltas (f32 dot t1.WD2 + softplus) into registers, reused in phases A & C.
// Phase B segmented: 512-thr local 16-scan, then 64-thr 8-segment combine.
// sout stored bf16 (RNE at store == gemm2's staging convert).
// ---------------------------------------------------------------------------
__global__ __launch_bounds__(512, 4)
void scan_fused_k(const float* __restrict__ xt, const float* __restrict__ pall,
                  const float* __restrict__ A, const float* __restrict__ Dv,
                  const float* __restrict__ WD2, const short* __restrict__ gt,
                  short* __restrict__ soutb) {
  __shared__ float Pl[DS * SD][SC + 1];   // 33024 B
  __shared__ float Hl[DS * SD][SC + 1];   // 33024 B
  __shared__ float Ps[DS * SD][NSEG + 1]; //  2304 B
  __shared__ float Hs[DS * SD][NSEG + 1]; //  2304 B
  const int blk = blockIdx.x;
  const int b   = blk >> 8;                // DM/SD = 256 blocks per batch
  const int d0  = (blk & 255) * SD;
  const int dd  = threadIdx.x & (SD - 1);
  const int c   = threadIdx.x >> 2;        // 0..127
  const int d   = d0 + dd;

  float e[DS];
#pragma unroll
  for (int s = 0; s < DS; s++) e[s] = expf(-A[d * DS + s]);

  const int nbase = b * L_ + c * SLC;
  const float* xrow = xt + (size_t)d * NROW;
  const short* grow = gt + (size_t)d * NROW;
  const float Dd = Dv[d];

  // ---- phase delta: dlt[t] = softplus(Dd + t1[n+t,:].WD2[d,:]) --------
  // t1 lives in pall cols 32..95; quad lanes read identical t1 addresses
  // (broadcast-merged); WD2 row register-tiled 16 wide to bound pressure.
  float dlt[SLC];
#pragma unroll
  for (int t = 0; t < SLC; t++) dlt[t] = Dd;
  {
    const float* wrow = WD2 + (size_t)d * DD;
#pragma unroll
    for (int kq = 0; kq < 4; kq++) {
      float4 w0 = *(const float4*)(wrow + kq * 16 + 0);
      float4 w1 = *(const float4*)(wrow + kq * 16 + 4);
      float4 w2 = *(const float4*)(wrow + kq * 16 + 8);
      float4 w3 = *(const float4*)(wrow + kq * 16 + 12);
#pragma unroll
      for (int t = 0; t < SLC; t++) {
        const float* trow = pall + (size_t)(nbase + t) * 96 + 32 + kq * 16;
        float4 a0 = *(const float4*)(trow + 0);
        float4 a1 = *(const float4*)(trow + 4);
        float4 a2 = *(const float4*)(trow + 8);
        float4 a3 = *(const float4*)(trow + 12);
        dlt[t] += a0.x * w0.x + a0.y * w0.y + a0.z * w0.z + a0.w * w0.w
                + a1.x * w1.x + a1.y * w1.y + a1.z * w1.z + a1.w * w1.w
                + a2.x * w2.x + a2.y * w2.y + a2.z * w2.z + a2.w * w2.w
                + a3.x * w3.x + a3.y * w3.y + a3.z * w3.z + a3.w * w3.w;
      }
    }
#pragma unroll
    for (int t = 0; t < SLC; t++) {
      float v = dlt[t];
      dlt[t] = fmaxf(v, 0.f) + log1pf(expf(-fabsf(v)));   // stable softplus
    }
  }

  // ---- phase A: local chunk scan, quad-batched ------------------------
  float h[DS];
#pragma unroll
  for (int s = 0; s < DS; s++) h[s] = 0.f;
  float pdl = 1.f;
#pragma unroll
  for (int q = 0; q < SLC / 4; q++) {
    const int n = nbase + q * 4;
    float4 x4 = *(const float4*)(xrow + n);
    float4 bq[4][4];
#pragma unroll
    for (int t = 0; t < 4; t++) {
      const float4* pp = (const float4*)(pall + (size_t)(n + t) * 96);
      bq[t][0] = pp[0]; bq[t][1] = pp[1]; bq[t][2] = pp[2]; bq[t][3] = pp[3];
    }
#pragma unroll
    for (int t = 0; t < 4; t++) {
      float dl = dlt[q * 4 + t], xv = (&x4.x)[t];
      float dx = dl * xv;
      pdl *= dl;
      float bmv[DS] = { bq[t][0].x, bq[t][0].y, bq[t][0].z, bq[t][0].w,
                        bq[t][1].x, bq[t][1].y, bq[t][1].z, bq[t][1].w,
                        bq[t][2].x, bq[t][2].y, bq[t][2].z, bq[t][2].w,
                        bq[t][3].x, bq[t][3].y, bq[t][3].z, bq[t][3].w };
#pragma unroll
      for (int s = 0; s < DS; s++)
        h[s] = (e[s] * dl) * h[s] + bmv[s] * dx;
    }
  }
#pragma unroll
  for (int s = 0; s < DS; s++) {
    float e2 = e[s] * e[s], e4 = e2 * e2, e8 = e4 * e4;   // e^SLC, SLC=8
    Pl[s * SD + dd][c] = e8 * pdl;
    Hl[s * SD + dd][c] = h[s];
  }
  __syncthreads();

  // ---- phase B1: 512 thr, 16-chunk local exclusive scans --------------
  {
    const int seg = threadIdx.x >> 6;       // 0..7
    const int cmb = threadIdx.x & 63;       // row
    float* Prow = &Pl[cmb][0];
    float* Hrow = &Hl[cmb][0];
    float Pa = 1.f, Ha = 0.f;
#pragma unroll
    for (int i = 0; i < SC / NSEG; i++) {
      int c2 = seg * (SC / NSEG) + i;
      float p = Prow[c2], hh = Hrow[c2];
      Prow[c2] = Pa;                        // local exclusive prefix product
      Hrow[c2] = Ha;                        // local exclusive prefix H
      Ha = p * Ha + hh;
      Pa *= p;
    }
    Ps[cmb][seg] = Pa;
    Hs[cmb][seg] = Ha;
  }
  __syncthreads();

  // ---- phase B2: 64 thr, serial combine of 8 segment carries ----------
  if (threadIdx.x < DS * SD) {
    float* Pr = &Ps[threadIdx.x][0];
    float* Hr = &Hs[threadIdx.x][0];
    float H = 0.f;
#pragma unroll
    for (int g = 0; g < NSEG; g++) {
      float p = Pr[g], hh = Hr[g];
      Hr[g] = H;                            // segment-exclusive carry-in
      H = p * H + hh;
    }
  }
  __syncthreads();

  // ---- phase C: replay with fused epilogue, quad-batched --------------
  {
    const int g = c >> 4;
#pragma unroll
    for (int s = 0; s < DS; s++)
      h[s] = Pl[s * SD + dd][c] * Hs[s * SD + dd][g] + Hl[s * SD + dd][c];
  }
#pragma unroll
  for (int q = 0; q < SLC / 4; q++) {
    const int n = nbase + q * 4;
    float4 x4 = *(const float4*)(xrow + n);
    short4v g4 = *(const short4v*)(grow + n);
    float4 bq[4][4], cq[4][4];
#pragma unroll
    for (int t = 0; t < 4; t++) {
      const float4* pp = (const float4*)(pall + (size_t)(n + t) * 96);
      bq[t][0] = pp[0]; bq[t][1] = pp[1]; bq[t][2] = pp[2]; bq[t][3] = pp[3];
      cq[t][0] = pp[4]; cq[t][1] = pp[5]; cq[t][2] = pp[6]; cq[t][3] = pp[7];
    }
#pragma unroll
    for (int t = 0; t < 4; t++) {
      float dl = dlt[q * 4 + t], xv = (&x4.x)[t];
      float dx = dl * xv;
      float bmv[DS] = { bq[t][0].x, bq[t][0].y, bq[t][0].z, bq[t][0].w,
                        bq[t][1].x, bq[t][1].y, bq[t][1].z, bq[t][1].w,
                        bq[t][2].x, bq[t][2].y, bq[t][2].z, bq[t][2].w,
                        bq[t][3].x, bq[t][3].y, bq[t][3].z, bq[t][3].w };
      float cmv[DS] = { cq[t][0].x, cq[t][0].y, cq[t][0].z, cq[t][0].w,
                        cq[t][1].x, cq[t][1].y, cq[t][1].z, cq[t][1].w,
                        cq[t][2].x, cq[t][2].y, cq[t][2].z, cq[t][2].w,
                        cq[t][3].x, cq[t][3].y, cq[t][3].z, cq[t][3].w };
      float y = 0.f;
#pragma unroll
      for (int s = 0; s < DS; s++) {
        h[s] = (e[s] * dl) * h[s] + bmv[s] * dx;
        y += h[s] * cmv[s];
      }
      y += Dd * xv;
      float gg = bf2f(g4[t]);
      soutb[(size_t)(n + t) * DM + d] = f2bf1(y * silu_f(gg));
    }
  }
}

// ---------------------------------------------------------------------------
// GEMM2: out[2048,512] = sout(bf16)[2048,1024] . Wout[512,1024]^T
// BM=64, BN=32 -> 512 blocks. 256 thr = 4 waves (2x2), wave tile 32x16.
// ---------------------------------------------------------------------------
__global__ __launch_bounds__(256)
void gemm2_k(const short* __restrict__ soutb, const float* __restrict__ Wout,
             float* __restrict__ out) {
  __shared__ short As[64 * 40];
  __shared__ short Bs[32 * 40];
  const int tid  = threadIdx.x;
  const int lane = tid & 63;
  const int wave = tid >> 6;
  const int r16  = lane & 15;
  const int quad = lane >> 4;
  const int m0 = blockIdx.y * 64;
  const int n0 = blockIdx.x * 32;
  const int wm = wave & 1, wn = wave >> 1;
  float4v acc[2];
  acc[0] = (float4v){0.f, 0.f, 0.f, 0.f};
  acc[1] = (float4v){0.f, 0.f, 0.f, 0.f};
  short8 pa;
  float4 pf0, pf1;
  auto ldu = [&](int k0) {
    {
      int row = tid >> 2, q = tid & 3;
      pa = *(const short8*)(soutb + (size_t)(m0 + row) * DM + k0 + q * 8);
    }
    if (tid < 128) {
      int row = tid >> 2, q = tid & 3;
      const float4* p = (const float4*)(Wout + (size_t)(n0 + row) * DM + k0 + q * 8);
      pf0 = p[0]; pf1 = p[1];
    }
  };
  auto stu = [&]() {
    { int row = tid >> 2, q = tid & 3; *(short8*)&As[row * 40 + q * 8] = pa; }
    if (tid < 128) { int row = tid >> 2, q = tid & 3; *(short8*)&Bs[row * 40 + q * 8] = pack8(pf0, pf1); }
  };
  ldu(0);
  for (int k0 = 0; k0 < DM; k0 += 32) {
    stu();
    __syncthreads();
    if (k0 + 32 < DM) ldu(k0 + 32);
    short8 afr[2], bfr;
    afr[0] = *(const short8*)&As[(wm * 32 + r16) * 40 + quad * 8];
    afr[1] = *(const short8*)&As[(wm * 32 + 16 + r16) * 40 + quad * 8];
    bfr    = *(const short8*)&Bs[(wn * 16 + r16) * 40 + quad * 8];
    acc[0] = __builtin_amdgcn_mfma_f32_16x16x32_bf16(afr[0], bfr, acc[0], 0, 0, 0);
    acc[1] = __builtin_amdgcn_mfma_f32_16x16x32_bf16(afr[1], bfr, acc[1], 0, 0, 0);
    __syncthreads();
  }
#pragma unroll
  for (int mi = 0; mi < 2; mi++)
#pragma unroll
    for (int r = 0; r < 4; r++)
      out[(size_t)(m0 + wm * 32 + mi * 16 + quad * 4 + r) * DIN + n0 + wn * 16 + r16] = acc[mi][r];
}

// ---------------------------------------------------------------------------
extern "C" void kernel_launch(void* const* d_in, const int* in_sizes, int n_in,
                              void* d_out, int out_size, void* d_ws, size_t ws_size,
                              hipStream_t stream) {
  const float* seq  = (const float*)d_in[0];
  const float* Win  = (const float*)d_in[1];
  const float* Wout = (const float*)d_in[2];
  const float* WB   = (const float*)d_in[3];
  const float* WC   = (const float*)d_in[4];
  const float* WD1  = (const float*)d_in[5];
  const float* WD2  = (const float*)d_in[6];
  const float* cw   = (const float*)d_in[7];
  const float* cb   = (const float*)d_in[8];
  const float* A    = (const float*)d_in[9];
  const float* Dv   = (const float*)d_in[10];
  float* out = (float*)d_out;

  float* ws = (float*)d_ws;
  __hip_bfloat16* ab = (__hip_bfloat16*)ws;       // 2048*2048 bf16
  float* xt   = ws   + 2097152;                   // 1024*2048 f32  (x transposed)
  short* gt   = (short*)(xt + 2097152);           // 1024*2048 bf16 (gate transposed)
  float* pall = (float*)(gt + 2097152);           // 2048*96 f32 (Bm|Cm|t1)
  short* soutb = (short*)(pall + 196608);         // 2048*1024 bf16
  // total ~27 MB (proven budget 47); dltT eliminated (delta fused into scan)

  gemm1_k<<<dim3(32, 32), 256, 0, stream>>>(seq, Win, ab, pall);
  convproj_k<<<1280, 256, 0, stream>>>(ab, cw, cb, WB, WC, WD1, xt, gt, pall);
  scan_fused_k<<<B_ * (DM / SD), 512, 0, stream>>>(xt, pall, A, Dv, WD2, gt, soutb);
  gemm2_k<<<dim3(16, 32), 256, 0, stream>>>(soutb, Wout, out);
}

// Round 3
// 182.221 us; speedup vs baseline: 1.6262x; 1.6262x over previous
//
#include <hip/hip_runtime.h>
#include <hip/hip_bf16.h>

typedef short short8 __attribute__((ext_vector_type(8)));
typedef short short4v __attribute__((ext_vector_type(4)));
typedef float float4v __attribute__((ext_vector_type(4)));

#define B_   2
#define L_   1024
#define DIN  512
#define DM   1024
#define DS   16
#define DD   64
#define KER_ 4
#define NROW (B_*L_)     // 2048

// scan geometry: block = (b, 4 d-lanes); 128 chunks x 8 steps = L, 512 thr
#define SD   4
#define SC   128
#define SLC  8
#define NSEG 8           // phase-B segments (SC/16)

__device__ __forceinline__ float silu_f(float v){ return v / (1.f + expf(-v)); }

__device__ __forceinline__ short2 f2bf2(float a, float b) {
  __hip_bfloat162 h = __float22bfloat162_rn(float2{a, b});
  union { __hip_bfloat162 h; short2 s; } u; u.h = h; return u.s;
}
__device__ __forceinline__ short f2bf1(float a) {
  __hip_bfloat16 h = __float2bfloat16(a);
  union { __hip_bfloat16 h; short s; } u; u.h = h; return u.s;
}
__device__ __forceinline__ short8 pack8(const float4& x0, const float4& x1) {
  short2 s0 = f2bf2(x0.x, x0.y), s1 = f2bf2(x0.z, x0.w);
  short2 s2 = f2bf2(x1.x, x1.y), s3 = f2bf2(x1.z, x1.w);
  return short8{ s0.x, s0.y, s1.x, s1.y, s2.x, s2.y, s3.x, s3.y };
}
__device__ __forceinline__ float bf2f(short s) {
  union { unsigned u; float f; } v; v.u = ((unsigned)(unsigned short)s) << 16; return v.f;
}

// ---------------------------------------------------------------------------
// GEMM1: ab[2048,2048](bf16) = seq[2048,512] . Win[2048,512]^T
// BM=BN=64, 256 thr = 4 waves (2x2), wave tile 32x32, BK=32, reg-prefetch.
// Also zeroes pall (disjoint from own writes; stream order covers proj).
// ---------------------------------------------------------------------------
__global__ __launch_bounds__(256)
void gemm1_k(const float* __restrict__ seq, const float* __restrict__ Win,
             __hip_bfloat16* __restrict__ ab, float* __restrict__ pall) {
  __shared__ short As[64 * 40];
  __shared__ short Bs[64 * 40];
  const int tid  = threadIdx.x;
  // fold-in: zero pall (196608 floats over 1024 blocks x 256 thr)
  {
    int zi = (blockIdx.y * 32 + blockIdx.x) * 256 + tid;
    if (zi < NROW * 96) pall[zi] = 0.f;
  }
  const int lane = tid & 63;
  const int wave = tid >> 6;
  const int r16  = lane & 15;
  const int quad = lane >> 4;
  const int m0 = blockIdx.y * 64;
  const int n0 = blockIdx.x * 64;
  const int wm = wave & 1, wn = wave >> 1;
  float4v acc[2][2];
#pragma unroll
  for (int i = 0; i < 2; i++)
#pragma unroll
    for (int j = 0; j < 2; j++) acc[i][j] = (float4v){0.f, 0.f, 0.f, 0.f};
  float4 pf0[2], pf1[2];
  auto ldu = [&](int j, int k0) {
    int u = tid + j * 256;
    const float4* p;
    if (u < 256) { int row = u >> 2, q = u & 3;
      p = (const float4*)(seq + (size_t)(m0 + row) * DIN + k0 + q * 8);
    } else { int v = u - 256; int row = v >> 2, q = v & 3;
      p = (const float4*)(Win + (size_t)(n0 + row) * DIN + k0 + q * 8);
    }
    pf0[j] = p[0]; pf1[j] = p[1];
  };
  auto stu = [&](int j) {
    int u = tid + j * 256;
    short8 s = pack8(pf0[j], pf1[j]);
    if (u < 256) { int row = u >> 2, q = u & 3; *(short8*)&As[row * 40 + q * 8] = s; }
    else { int v = u - 256; int row = v >> 2, q = v & 3; *(short8*)&Bs[row * 40 + q * 8] = s; }
  };
  ldu(0, 0); ldu(1, 0);
  for (int k0 = 0; k0 < DIN; k0 += 32) {
    stu(0); stu(1);
    __syncthreads();
    if (k0 + 32 < DIN) { ldu(0, k0 + 32); ldu(1, k0 + 32); }
    short8 afr[2], bfr[2];
#pragma unroll
    for (int mi = 0; mi < 2; mi++)
      afr[mi] = *(const short8*)&As[(wm * 32 + mi * 16 + r16) * 40 + quad * 8];
#pragma unroll
    for (int ni = 0; ni < 2; ni++)
      bfr[ni] = *(const short8*)&Bs[(wn * 32 + ni * 16 + r16) * 40 + quad * 8];
#pragma unroll
    for (int mi = 0; mi < 2; mi++)
#pragma unroll
      for (int ni = 0; ni < 2; ni++)
        acc[mi][ni] = __builtin_amdgcn_mfma_f32_16x16x32_bf16(afr[mi], bfr[ni], acc[mi][ni], 0, 0, 0);
    __syncthreads();
  }
#pragma unroll
  for (int mi = 0; mi < 2; mi++)
#pragma unroll
    for (int ni = 0; ni < 2; ni++) {
      int gn = n0 + wn * 32 + ni * 16 + r16;
#pragma unroll
      for (int r = 0; r < 4; r++) {
        int gm = m0 + wm * 32 + mi * 16 + quad * 4 + r;
        ab[(size_t)gm * (2 * DM) + gn] = __float2bfloat16(acc[mi][ni][r]);
      }
    }
}

// ---------------------------------------------------------------------------
// convT + proj merged (independent consumers of ab; block-range split).
// blk < 1024: convT tile -> xT (f32, silu(conv)) / gT (bf16 gate transpose).
// blk >= 1024: proj split-K block -> pall atomicAdd (pall zeroed by gemm1).
// ---------------------------------------------------------------------------
__global__ __launch_bounds__(256)
void convproj_k(const __hip_bfloat16* __restrict__ ab, const float* __restrict__ cw,
                const float* __restrict__ cb, const float* __restrict__ WB,
                const float* __restrict__ WC, const float* __restrict__ WD1,
                float* __restrict__ xt, short* __restrict__ gt,
                float* __restrict__ pall) {
  __shared__ char smraw[12800];
  const int blk = blockIdx.x;
  const int tid = threadIdx.x;

  if (blk < 1024) {
    // ---------------- convT (verbatim R13 body) -------------------------
    short* tile = (short*)smraw;               // 67*74 shorts = 9916 B
    const int n0 = (blk & 31) * 64;
    const int d0 = (blk >> 5) * 64;            // 0..2047
    const int l0 = n0 & (L_ - 1);
    for (int u = tid; u < 67 * 8; u += 256) {
      int r = u >> 3, c8 = u & 7;
      int l = l0 - 3 + r;
      short8 v = short8{0, 0, 0, 0, 0, 0, 0, 0};
      if (l >= 0 && r < 67)
        v = *(const short8*)(ab + (size_t)(n0 - l0 + l) * (2 * DM) + d0 + c8 * 8);
      *(short8*)&tile[r * 74 + c8 * 8] = v;
    }
    __syncthreads();
    const int i  = tid & 63;
    const int dl = tid >> 6;                   // 0..3
    if (d0 < DM) {
#pragma unroll 4
      for (int p = 0; p < 16; p++) {
        int dc = p * 4 + dl;
        int d  = d0 + dc;
        float4 w = *(const float4*)(cw + d * 4);
        float a = cb[d];
        a += bf2f(tile[(i + 0) * 74 + dc]) * w.x;
        a += bf2f(tile[(i + 1) * 74 + dc]) * w.y;
        a += bf2f(tile[(i + 2) * 74 + dc]) * w.z;
        a += bf2f(tile[(i + 3) * 74 + dc]) * w.w;
        xt[(size_t)d * NROW + n0 + i] = silu_f(a);
      }
    } else {
#pragma unroll 4
      for (int p = 0; p < 16; p++) {
        int dc = p * 4 + dl;
        gt[(size_t)(d0 - DM + dc) * NROW + n0 + i] = tile[(i + 3) * 74 + dc];
      }
    }
    return;
  }

  // ---------------- proj (verbatim R13 body) ----------------------------
  short* As = (short*)smraw;                   // 64*40
  short* Bs = As + 64 * 40;                    // 96*40  (total 12800 B)
  const int b2   = blk - 1024;                 // 0..255
  const int lane = tid & 63;
  const int wave = tid >> 6;
  const int r16  = lane & 15;
  const int quad = lane >> 4;
  const int m0   = (b2 & 31) * 64;
  const int kbeg = (b2 >> 5) * 128;
  float4v acc[6];
#pragma unroll
  for (int i = 0; i < 6; i++) acc[i] = (float4v){0.f, 0.f, 0.f, 0.f};

  short8 ta[KER_];
  float4 pf0[2], pf1[2];
  const int arow = tid >> 2, aq = tid & 3;
  const int an = m0 + arow, al = an & (L_ - 1), abq = an >> 10;

  auto ldu_a = [&](int k0) {
#pragma unroll
    for (int t = 0; t < KER_; t++) {
      int ll = al - (KER_ - 1) + t;
      if (ll >= 0)
        ta[t] = *(const short8*)(ab + (size_t)(abq * L_ + ll) * (2 * DM) + k0 + aq * 8);
      else
        ta[t] = short8{0, 0, 0, 0, 0, 0, 0, 0};
    }
  };
  auto stu_a = [&](int k0) {
    float r8[8];
#pragma unroll
    for (int e = 0; e < 8; e++) {
      int d = k0 + aq * 8 + e;
      float4 w = *(const float4*)(cw + d * 4);
      float a = cb[d];
      a += bf2f(ta[0][e]) * w.x;
      a += bf2f(ta[1][e]) * w.y;
      a += bf2f(ta[2][e]) * w.z;
      a += bf2f(ta[3][e]) * w.w;
      r8[e] = silu_f(a);
    }
    *(short8*)&As[arow * 40 + aq * 8] =
        pack8(float4{r8[0], r8[1], r8[2], r8[3]}, float4{r8[4], r8[5], r8[6], r8[7]});
  };
  auto ldu_b = [&](int j, int k0) {
    int u = tid + j * 256;
    if (u >= 640) return;
    int v = u - 256, row = v >> 2, q = v & 3;
    const float* bp = (row < 16) ? (WB + (size_t)row * DM)
                    : (row < 32) ? (WC + (size_t)(row - 16) * DM)
                                 : (WD1 + (size_t)(row - 32) * DM);
    const float4* p = (const float4*)(bp + k0 + q * 8);
    pf0[j - 1] = p[0]; pf1[j - 1] = p[1];
  };
  auto stu_b = [&](int j) {
    int u = tid + j * 256;
    if (u >= 640) return;
    int v = u - 256, row = v >> 2, q = v & 3;
    *(short8*)&Bs[row * 40 + q * 8] = pack8(pf0[j - 1], pf1[j - 1]);
  };

  ldu_a(kbeg); ldu_b(1, kbeg); ldu_b(2, kbeg);
  for (int k0 = kbeg; k0 < kbeg + 128; k0 += 32) {
    stu_a(k0); stu_b(1); stu_b(2);
    __syncthreads();
    if (k0 + 32 < kbeg + 128) { ldu_a(k0 + 32); ldu_b(1, k0 + 32); ldu_b(2, k0 + 32); }
    short8 afr = *(const short8*)&As[(wave * 16 + r16) * 40 + quad * 8];
#pragma unroll
    for (int ni = 0; ni < 6; ni++) {
      short8 bfr = *(const short8*)&Bs[(ni * 16 + r16) * 40 + quad * 8];
      acc[ni] = __builtin_amdgcn_mfma_f32_16x16x32_bf16(afr, bfr, acc[ni], 0, 0, 0);
    }
    __syncthreads();
  }
#pragma unroll
  for (int ni = 0; ni < 6; ni++) {
    int gn = ni * 16 + r16;
#pragma unroll
    for (int r = 0; r < 4; r++) {
      int gm = m0 + wave * 16 + quad * 4 + r;
      atomicAdd(&pall[(size_t)gm * 96 + gn], acc[ni][r]);
    }
  }
}

// ---------------------------------------------------------------------------
// Fused selective scan. R16: same structure as R15 (delta fused, segmented
// phase B) but spill-fixed: __launch_bounds__(512,2) lifts the VGPR cap to
// 256 (R15's (512,4) made the allocator target 64 VGPR -> ~520 MB scratch
// traffic); e[] moved after the delta dot to shrink its live set.
// ---------------------------------------------------------------------------
__global__ __launch_bounds__(512, 2)
void scan_fused_k(const float* __restrict__ xt, const float* __restrict__ pall,
                  const float* __restrict__ A, const float* __restrict__ Dv,
                  const float* __restrict__ WD2, const short* __restrict__ gt,
                  short* __restrict__ soutb) {
  __shared__ float Pl[DS * SD][SC + 1];   // 33024 B
  __shared__ float Hl[DS * SD][SC + 1];   // 33024 B
  __shared__ float Ps[DS * SD][NSEG + 1]; //  2304 B
  __shared__ float Hs[DS * SD][NSEG + 1]; //  2304 B
  const int blk = blockIdx.x;
  const int b   = blk >> 8;                // DM/SD = 256 blocks per batch
  const int d0  = (blk & 255) * SD;
  const int dd  = threadIdx.x & (SD - 1);
  const int c   = threadIdx.x >> 2;        // 0..127
  const int d   = d0 + dd;

  const int nbase = b * L_ + c * SLC;
  const float* xrow = xt + (size_t)d * NROW;
  const short* grow = gt + (size_t)d * NROW;
  const float Dd = Dv[d];

  // ---- phase delta: dlt[t] = softplus(Dd + t1[n+t,:].WD2[d,:]) --------
  // t1 lives in pall cols 32..95; quad lanes read identical t1 addresses
  // (broadcast-merged); WD2 row register-tiled 16 wide to bound pressure.
  float dlt[SLC];
#pragma unroll
  for (int t = 0; t < SLC; t++) dlt[t] = Dd;
  {
    const float* wrow = WD2 + (size_t)d * DD;
#pragma unroll
    for (int kq = 0; kq < 4; kq++) {
      float4 w0 = *(const float4*)(wrow + kq * 16 + 0);
      float4 w1 = *(const float4*)(wrow + kq * 16 + 4);
      float4 w2 = *(const float4*)(wrow + kq * 16 + 8);
      float4 w3 = *(const float4*)(wrow + kq * 16 + 12);
#pragma unroll
      for (int t = 0; t < SLC; t++) {
        const float* trow = pall + (size_t)(nbase + t) * 96 + 32 + kq * 16;
        float4 a0 = *(const float4*)(trow + 0);
        float4 a1 = *(const float4*)(trow + 4);
        float4 a2 = *(const float4*)(trow + 8);
        float4 a3 = *(const float4*)(trow + 12);
        dlt[t] += a0.x * w0.x + a0.y * w0.y + a0.z * w0.z + a0.w * w0.w
                + a1.x * w1.x + a1.y * w1.y + a1.z * w1.z + a1.w * w1.w
                + a2.x * w2.x + a2.y * w2.y + a2.z * w2.z + a2.w * w2.w
                + a3.x * w3.x + a3.y * w3.y + a3.z * w3.z + a3.w * w3.w;
      }
    }
#pragma unroll
    for (int t = 0; t < SLC; t++) {
      float v = dlt[t];
      dlt[t] = fmaxf(v, 0.f) + log1pf(expf(-fabsf(v)));   // stable softplus
    }
  }

  // e[] computed AFTER the delta dot (keeps it out of that live range)
  float e[DS];
#pragma unroll
  for (int s = 0; s < DS; s++) e[s] = expf(-A[d * DS + s]);

  // ---- phase A: local chunk scan, quad-batched ------------------------
  float h[DS];
#pragma unroll
  for (int s = 0; s < DS; s++) h[s] = 0.f;
  float pdl = 1.f;
#pragma unroll
  for (int q = 0; q < SLC / 4; q++) {
    const int n = nbase + q * 4;
    float4 x4 = *(const float4*)(xrow + n);
    float4 bq[4][4];
#pragma unroll
    for (int t = 0; t < 4; t++) {
      const float4* pp = (const float4*)(pall + (size_t)(n + t) * 96);
      bq[t][0] = pp[0]; bq[t][1] = pp[1]; bq[t][2] = pp[2]; bq[t][3] = pp[3];
    }
#pragma unroll
    for (int t = 0; t < 4; t++) {
      float dl = dlt[q * 4 + t], xv = (&x4.x)[t];
      float dx = dl * xv;
      pdl *= dl;
      float bmv[DS] = { bq[t][0].x, bq[t][0].y, bq[t][0].z, bq[t][0].w,
                        bq[t][1].x, bq[t][1].y, bq[t][1].z, bq[t][1].w,
                        bq[t][2].x, bq[t][2].y, bq[t][2].z, bq[t][2].w,
                        bq[t][3].x, bq[t][3].y, bq[t][3].z, bq[t][3].w };
#pragma unroll
      for (int s = 0; s < DS; s++)
        h[s] = (e[s] * dl) * h[s] + bmv[s] * dx;
    }
  }
#pragma unroll
  for (int s = 0; s < DS; s++) {
    float e2 = e[s] * e[s], e4 = e2 * e2, e8 = e4 * e4;   // e^SLC, SLC=8
    Pl[s * SD + dd][c] = e8 * pdl;
    Hl[s * SD + dd][c] = h[s];
  }
  __syncthreads();

  // ---- phase B1: 512 thr, 16-chunk local exclusive scans --------------
  {
    const int seg = threadIdx.x >> 6;       // 0..7
    const int cmb = threadIdx.x & 63;       // row
    float* Prow = &Pl[cmb][0];
    float* Hrow = &Hl[cmb][0];
    float Pa = 1.f, Ha = 0.f;
#pragma unroll
    for (int i = 0; i < SC / NSEG; i++) {
      int c2 = seg * (SC / NSEG) + i;
      float p = Prow[c2], hh = Hrow[c2];
      Prow[c2] = Pa;                        // local exclusive prefix product
      Hrow[c2] = Ha;                        // local exclusive prefix H
      Ha = p * Ha + hh;
      Pa *= p;
    }
    Ps[cmb][seg] = Pa;
    Hs[cmb][seg] = Ha;
  }
  __syncthreads();

  // ---- phase B2: 64 thr, serial combine of 8 segment carries ----------
  if (threadIdx.x < DS * SD) {
    float* Pr = &Ps[threadIdx.x][0];
    float* Hr = &Hs[threadIdx.x][0];
    float H = 0.f;
#pragma unroll
    for (int g = 0; g < NSEG; g++) {
      float p = Pr[g], hh = Hr[g];
      Hr[g] = H;                            // segment-exclusive carry-in
      H = p * H + hh;
    }
  }
  __syncthreads();

  // ---- phase C: replay with fused epilogue, quad-batched --------------
  {
    const int g = c >> 4;
#pragma unroll
    for (int s = 0; s < DS; s++)
      h[s] = Pl[s * SD + dd][c] * Hs[s * SD + dd][g] + Hl[s * SD + dd][c];
  }
#pragma unroll
  for (int q = 0; q < SLC / 4; q++) {
    const int n = nbase + q * 4;
    float4 x4 = *(const float4*)(xrow + n);
    short4v g4 = *(const short4v*)(grow + n);
    float4 bq[4][4], cq[4][4];
#pragma unroll
    for (int t = 0; t < 4; t++) {
      const float4* pp = (const float4*)(pall + (size_t)(n + t) * 96);
      bq[t][0] = pp[0]; bq[t][1] = pp[1]; bq[t][2] = pp[2]; bq[t][3] = pp[3];
      cq[t][0] = pp[4]; cq[t][1] = pp[5]; cq[t][2] = pp[6]; cq[t][3] = pp[7];
    }
#pragma unroll
    for (int t = 0; t < 4; t++) {
      float dl = dlt[q * 4 + t], xv = (&x4.x)[t];
      float dx = dl * xv;
      float bmv[DS] = { bq[t][0].x, bq[t][0].y, bq[t][0].z, bq[t][0].w,
                        bq[t][1].x, bq[t][1].y, bq[t][1].z, bq[t][1].w,
                        bq[t][2].x, bq[t][2].y, bq[t][2].z, bq[t][2].w,
                        bq[t][3].x, bq[t][3].y, bq[t][3].z, bq[t][3].w };
      float cmv[DS] = { cq[t][0].x, cq[t][0].y, cq[t][0].z, cq[t][0].w,
                        cq[t][1].x, cq[t][1].y, cq[t][1].z, cq[t][1].w,
                        cq[t][2].x, cq[t][2].y, cq[t][2].z, cq[t][2].w,
                        cq[t][3].x, cq[t][3].y, cq[t][3].z, cq[t][3].w };
      float y = 0.f;
#pragma unroll
      for (int s = 0; s < DS; s++) {
        h[s] = (e[s] * dl) * h[s] + bmv[s] * dx;
        y += h[s] * cmv[s];
      }
      y += Dd * xv;
      float gg = bf2f(g4[t]);
      soutb[(size_t)(n + t) * DM + d] = f2bf1(y * silu_f(gg));
    }
  }
}

// ---------------------------------------------------------------------------
// GEMM2: out[2048,512] = sout(bf16)[2048,1024] . Wout[512,1024]^T
// BM=64, BN=32 -> 512 blocks. 256 thr = 4 waves (2x2), wave tile 32x16.
// ---------------------------------------------------------------------------
__global__ __launch_bounds__(256)
void gemm2_k(const short* __restrict__ soutb, const float* __restrict__ Wout,
             float* __restrict__ out) {
  __shared__ short As[64 * 40];
  __shared__ short Bs[32 * 40];
  const int tid  = threadIdx.x;
  const int lane = tid & 63;
  const int wave = tid >> 6;
  const int r16  = lane & 15;
  const int quad = lane >> 4;
  const int m0 = blockIdx.y * 64;
  const int n0 = blockIdx.x * 32;
  const int wm = wave & 1, wn = wave >> 1;
  float4v acc[2];
  acc[0] = (float4v){0.f, 0.f, 0.f, 0.f};
  acc[1] = (float4v){0.f, 0.f, 0.f, 0.f};
  short8 pa;
  float4 pf0, pf1;
  auto ldu = [&](int k0) {
    {
      int row = tid >> 2, q = tid & 3;
      pa = *(const short8*)(soutb + (size_t)(m0 + row) * DM + k0 + q * 8);
    }
    if (tid < 128) {
      int row = tid >> 2, q = tid & 3;
      const float4* p = (const float4*)(Wout + (size_t)(n0 + row) * DM + k0 + q * 8);
      pf0 = p[0]; pf1 = p[1];
    }
  };
  auto stu = [&]() {
    { int row = tid >> 2, q = tid & 3; *(short8*)&As[row * 40 + q * 8] = pa; }
    if (tid < 128) { int row = tid >> 2, q = tid & 3; *(short8*)&Bs[row * 40 + q * 8] = pack8(pf0, pf1); }
  };
  ldu(0);
  for (int k0 = 0; k0 < DM; k0 += 32) {
    stu();
    __syncthreads();
    if (k0 + 32 < DM) ldu(k0 + 32);
    short8 afr[2], bfr;
    afr[0] = *(const short8*)&As[(wm * 32 + r16) * 40 + quad * 8];
    afr[1] = *(const short8*)&As[(wm * 32 + 16 + r16) * 40 + quad * 8];
    bfr    = *(const short8*)&Bs[(wn * 16 + r16) * 40 + quad * 8];
    acc[0] = __builtin_amdgcn_mfma_f32_16x16x32_bf16(afr[0], bfr, acc[0], 0, 0, 0);
    acc[1] = __builtin_amdgcn_mfma_f32_16x16x32_bf16(afr[1], bfr, acc[1], 0, 0, 0);
    __syncthreads();
  }
#pragma unroll
  for (int mi = 0; mi < 2; mi++)
#pragma unroll
    for (int r = 0; r < 4; r++)
      out[(size_t)(m0 + wm * 32 + mi * 16 + quad * 4 + r) * DIN + n0 + wn * 16 + r16] = acc[mi][r];
}

// ---------------------------------------------------------------------------
extern "C" void kernel_launch(void* const* d_in, const int* in_sizes, int n_in,
                              void* d_out, int out_size, void* d_ws, size_t ws_size,
                              hipStream_t stream) {
  const float* seq  = (const float*)d_in[0];
  const float* Win  = (const float*)d_in[1];
  const float* Wout = (const float*)d_in[2];
  const float* WB   = (const float*)d_in[3];
  const float* WC   = (const float*)d_in[4];
  const float* WD1  = (const float*)d_in[5];
  const float* WD2  = (const float*)d_in[6];
  const float* cw   = (const float*)d_in[7];
  const float* cb   = (const float*)d_in[8];
  const float* A    = (const float*)d_in[9];
  const float* Dv   = (const float*)d_in[10];
  float* out = (float*)d_out;

  float* ws = (float*)d_ws;
  __hip_bfloat16* ab = (__hip_bfloat16*)ws;       // 2048*2048 bf16
  float* xt   = ws   + 2097152;                   // 1024*2048 f32  (x transposed)
  short* gt   = (short*)(xt + 2097152);           // 1024*2048 bf16 (gate transposed)
  float* pall = (float*)(gt + 2097152);           // 2048*96 f32 (Bm|Cm|t1)
  short* soutb = (short*)(pall + 196608);         // 2048*1024 bf16
  // total ~27 MB (proven budget 47); dltT eliminated (delta fused into scan)

  gemm1_k<<<dim3(32, 32), 256, 0, stream>>>(seq, Win, ab, pall);
  convproj_k<<<1280, 256, 0, stream>>>(ab, cw, cb, WB, WC, WD1, xt, gt, pall);
  scan_fused_k<<<B_ * (DM / SD), 512, 0, stream>>>(xt, pall, A, Dv, WD2, gt, soutb);
  gemm2_k<<<dim3(16, 32), 256, 0, stream>>>(soutb, Wout, out);
}

// Round 4
// 162.084 us; speedup vs baseline: 1.8282x; 1.1242x over previous
//
#include <hip/hip_runtime.h>
#include <hip/hip_bf16.h>

typedef short short8 __attribute__((ext_vector_type(8)));
typedef short short4v __attribute__((ext_vector_type(4)));
typedef float float4v __attribute__((ext_vector_type(4)));

#define B_   2
#define L_   1024
#define DIN  512
#define DM   1024
#define DS   16
#define DD   64
#define KER_ 4
#define NROW (B_*L_)     // 2048

// scan geometry: block = (b, 4 d-lanes); 128 chunks x 8 steps = L, 512 thr
#define SD   4
#define SC   128
#define SLC  8
#define NSEG 8           // phase-B segments (SC/16)

__device__ __forceinline__ float silu_f(float v){ return v / (1.f + expf(-v)); }

__device__ __forceinline__ short2 f2bf2(float a, float b) {
  __hip_bfloat162 h = __float22bfloat162_rn(float2{a, b});
  union { __hip_bfloat162 h; short2 s; } u; u.h = h; return u.s;
}
__device__ __forceinline__ short f2bf1(float a) {
  __hip_bfloat16 h = __float2bfloat16(a);
  union { __hip_bfloat16 h; short s; } u; u.h = h; return u.s;
}
__device__ __forceinline__ short8 pack8(const float4& x0, const float4& x1) {
  short2 s0 = f2bf2(x0.x, x0.y), s1 = f2bf2(x0.z, x0.w);
  short2 s2 = f2bf2(x1.x, x1.y), s3 = f2bf2(x1.z, x1.w);
  return short8{ s0.x, s0.y, s1.x, s1.y, s2.x, s2.y, s3.x, s3.y };
}
__device__ __forceinline__ float bf2f(short s) {
  union { unsigned u; float f; } v; v.u = ((unsigned)(unsigned short)s) << 16; return v.f;
}

// ---------------------------------------------------------------------------
// GEMM1: ab[2048,2048](bf16) = seq[2048,512] . Win[2048,512]^T
// BM=BN=64, 256 thr = 4 waves (2x2), wave tile 32x32, BK=32, reg-prefetch.
// Also zeroes pall (disjoint from own writes; stream order covers proj).
// ---------------------------------------------------------------------------
__global__ __launch_bounds__(256)
void gemm1_k(const float* __restrict__ seq, const float* __restrict__ Win,
             __hip_bfloat16* __restrict__ ab, float* __restrict__ pall) {
  __shared__ short As[64 * 40];
  __shared__ short Bs[64 * 40];
  const int tid  = threadIdx.x;
  // fold-in: zero pall (196608 floats over 1024 blocks x 256 thr)
  {
    int zi = (blockIdx.y * 32 + blockIdx.x) * 256 + tid;
    if (zi < NROW * 96) pall[zi] = 0.f;
  }
  const int lane = tid & 63;
  const int wave = tid >> 6;
  const int r16  = lane & 15;
  const int quad = lane >> 4;
  const int m0 = blockIdx.y * 64;
  const int n0 = blockIdx.x * 64;
  const int wm = wave & 1, wn = wave >> 1;
  float4v acc[2][2];
#pragma unroll
  for (int i = 0; i < 2; i++)
#pragma unroll
    for (int j = 0; j < 2; j++) acc[i][j] = (float4v){0.f, 0.f, 0.f, 0.f};
  float4 pf0[2], pf1[2];
  auto ldu = [&](int j, int k0) {
    int u = tid + j * 256;
    const float4* p;
    if (u < 256) { int row = u >> 2, q = u & 3;
      p = (const float4*)(seq + (size_t)(m0 + row) * DIN + k0 + q * 8);
    } else { int v = u - 256; int row = v >> 2, q = v & 3;
      p = (const float4*)(Win + (size_t)(n0 + row) * DIN + k0 + q * 8);
    }
    pf0[j] = p[0]; pf1[j] = p[1];
  };
  auto stu = [&](int j) {
    int u = tid + j * 256;
    short8 s = pack8(pf0[j], pf1[j]);
    if (u < 256) { int row = u >> 2, q = u & 3; *(short8*)&As[row * 40 + q * 8] = s; }
    else { int v = u - 256; int row = v >> 2, q = v & 3; *(short8*)&Bs[row * 40 + q * 8] = s; }
  };
  ldu(0, 0); ldu(1, 0);
  for (int k0 = 0; k0 < DIN; k0 += 32) {
    stu(0); stu(1);
    __syncthreads();
    if (k0 + 32 < DIN) { ldu(0, k0 + 32); ldu(1, k0 + 32); }
    short8 afr[2], bfr[2];
#pragma unroll
    for (int mi = 0; mi < 2; mi++)
      afr[mi] = *(const short8*)&As[(wm * 32 + mi * 16 + r16) * 40 + quad * 8];
#pragma unroll
    for (int ni = 0; ni < 2; ni++)
      bfr[ni] = *(const short8*)&Bs[(wn * 32 + ni * 16 + r16) * 40 + quad * 8];
#pragma unroll
    for (int mi = 0; mi < 2; mi++)
#pragma unroll
      for (int ni = 0; ni < 2; ni++)
        acc[mi][ni] = __builtin_amdgcn_mfma_f32_16x16x32_bf16(afr[mi], bfr[ni], acc[mi][ni], 0, 0, 0);
    __syncthreads();
  }
#pragma unroll
  for (int mi = 0; mi < 2; mi++)
#pragma unroll
    for (int ni = 0; ni < 2; ni++) {
      int gn = n0 + wn * 32 + ni * 16 + r16;
#pragma unroll
      for (int r = 0; r < 4; r++) {
        int gm = m0 + wm * 32 + mi * 16 + quad * 4 + r;
        ab[(size_t)gm * (2 * DM) + gn] = __float2bfloat16(acc[mi][ni][r]);
      }
    }
}

// ---------------------------------------------------------------------------
// convT + proj merged (independent consumers of ab; block-range split).
// blk < 1024: convT tile -> xT (f32, silu(conv)) / gT (bf16 gate transpose).
// blk >= 1024: proj split-K block -> pall atomicAdd (pall zeroed by gemm1).
// ---------------------------------------------------------------------------
__global__ __launch_bounds__(256)
void convproj_k(const __hip_bfloat16* __restrict__ ab, const float* __restrict__ cw,
                const float* __restrict__ cb, const float* __restrict__ WB,
                const float* __restrict__ WC, const float* __restrict__ WD1,
                float* __restrict__ xt, short* __restrict__ gt,
                float* __restrict__ pall) {
  __shared__ char smraw[12800];
  const int blk = blockIdx.x;
  const int tid = threadIdx.x;

  if (blk < 1024) {
    // ---------------- convT (verbatim R13 body) -------------------------
    short* tile = (short*)smraw;               // 67*74 shorts = 9916 B
    const int n0 = (blk & 31) * 64;
    const int d0 = (blk >> 5) * 64;            // 0..2047
    const int l0 = n0 & (L_ - 1);
    for (int u = tid; u < 67 * 8; u += 256) {
      int r = u >> 3, c8 = u & 7;
      int l = l0 - 3 + r;
      short8 v = short8{0, 0, 0, 0, 0, 0, 0, 0};
      if (l >= 0 && r < 67)
        v = *(const short8*)(ab + (size_t)(n0 - l0 + l) * (2 * DM) + d0 + c8 * 8);
      *(short8*)&tile[r * 74 + c8 * 8] = v;
    }
    __syncthreads();
    const int i  = tid & 63;
    const int dl = tid >> 6;                   // 0..3
    if (d0 < DM) {
#pragma unroll 4
      for (int p = 0; p < 16; p++) {
        int dc = p * 4 + dl;
        int d  = d0 + dc;
        float4 w = *(const float4*)(cw + d * 4);
        float a = cb[d];
        a += bf2f(tile[(i + 0) * 74 + dc]) * w.x;
        a += bf2f(tile[(i + 1) * 74 + dc]) * w.y;
        a += bf2f(tile[(i + 2) * 74 + dc]) * w.z;
        a += bf2f(tile[(i + 3) * 74 + dc]) * w.w;
        xt[(size_t)d * NROW + n0 + i] = silu_f(a);
      }
    } else {
#pragma unroll 4
      for (int p = 0; p < 16; p++) {
        int dc = p * 4 + dl;
        gt[(size_t)(d0 - DM + dc) * NROW + n0 + i] = tile[(i + 3) * 74 + dc];
      }
    }
    return;
  }

  // ---------------- proj (verbatim R13 body) ----------------------------
  short* As = (short*)smraw;                   // 64*40
  short* Bs = As + 64 * 40;                    // 96*40  (total 12800 B)
  const int b2   = blk - 1024;                 // 0..255
  const int lane = tid & 63;
  const int wave = tid >> 6;
  const int r16  = lane & 15;
  const int quad = lane >> 4;
  const int m0   = (b2 & 31) * 64;
  const int kbeg = (b2 >> 5) * 128;
  float4v acc[6];
#pragma unroll
  for (int i = 0; i < 6; i++) acc[i] = (float4v){0.f, 0.f, 0.f, 0.f};

  short8 ta[KER_];
  float4 pf0[2], pf1[2];
  const int arow = tid >> 2, aq = tid & 3;
  const int an = m0 + arow, al = an & (L_ - 1), abq = an >> 10;

  auto ldu_a = [&](int k0) {
#pragma unroll
    for (int t = 0; t < KER_; t++) {
      int ll = al - (KER_ - 1) + t;
      if (ll >= 0)
        ta[t] = *(const short8*)(ab + (size_t)(abq * L_ + ll) * (2 * DM) + k0 + aq * 8);
      else
        ta[t] = short8{0, 0, 0, 0, 0, 0, 0, 0};
    }
  };
  auto stu_a = [&](int k0) {
    float r8[8];
#pragma unroll
    for (int e = 0; e < 8; e++) {
      int d = k0 + aq * 8 + e;
      float4 w = *(const float4*)(cw + d * 4);
      float a = cb[d];
      a += bf2f(ta[0][e]) * w.x;
      a += bf2f(ta[1][e]) * w.y;
      a += bf2f(ta[2][e]) * w.z;
      a += bf2f(ta[3][e]) * w.w;
      r8[e] = silu_f(a);
    }
    *(short8*)&As[arow * 40 + aq * 8] =
        pack8(float4{r8[0], r8[1], r8[2], r8[3]}, float4{r8[4], r8[5], r8[6], r8[7]});
  };
  auto ldu_b = [&](int j, int k0) {
    int u = tid + j * 256;
    if (u >= 640) return;
    int v = u - 256, row = v >> 2, q = v & 3;
    const float* bp = (row < 16) ? (WB + (size_t)row * DM)
                    : (row < 32) ? (WC + (size_t)(row - 16) * DM)
                                 : (WD1 + (size_t)(row - 32) * DM);
    const float4* p = (const float4*)(bp + k0 + q * 8);
    pf0[j - 1] = p[0]; pf1[j - 1] = p[1];
  };
  auto stu_b = [&](int j) {
    int u = tid + j * 256;
    if (u >= 640) return;
    int v = u - 256, row = v >> 2, q = v & 3;
    *(short8*)&Bs[row * 40 + q * 8] = pack8(pf0[j - 1], pf1[j - 1]);
  };

  ldu_a(kbeg); ldu_b(1, kbeg); ldu_b(2, kbeg);
  for (int k0 = kbeg; k0 < kbeg + 128; k0 += 32) {
    stu_a(k0); stu_b(1); stu_b(2);
    __syncthreads();
    if (k0 + 32 < kbeg + 128) { ldu_a(k0 + 32); ldu_b(1, k0 + 32); ldu_b(2, k0 + 32); }
    short8 afr = *(const short8*)&As[(wave * 16 + r16) * 40 + quad * 8];
#pragma unroll
    for (int ni = 0; ni < 6; ni++) {
      short8 bfr = *(const short8*)&Bs[(ni * 16 + r16) * 40 + quad * 8];
      acc[ni] = __builtin_amdgcn_mfma_f32_16x16x32_bf16(afr, bfr, acc[ni], 0, 0, 0);
    }
    __syncthreads();
  }
#pragma unroll
  for (int ni = 0; ni < 6; ni++) {
    int gn = ni * 16 + r16;
#pragma unroll
    for (int r = 0; r < 4; r++) {
      int gm = m0 + wave * 16 + quad * 4 + r;
      atomicAdd(&pall[(size_t)gm * 96 + gn], acc[ni][r]);
    }
  }
}

// ---------------------------------------------------------------------------
// delta: dltT[1024,2048] = softplus(t1 . WD2^T + Dv)^T  (transposed store)
// (restored: MFMA path is ~10x cheaper than per-thread VALU dot in the scan)
// ---------------------------------------------------------------------------
__global__ __launch_bounds__(256)
void delta_k(const float* __restrict__ t1, const float* __restrict__ WD2,
             const float* __restrict__ Dv, float* __restrict__ dltT) {
  __shared__ short As[64 * 40];
  __shared__ short Bs[64 * 40];
  const int tid  = threadIdx.x;
  const int lane = tid & 63;
  const int wave = tid >> 6;
  const int r16  = lane & 15;
  const int quad = lane >> 4;
  const int m0 = blockIdx.y * 64;
  const int n0 = blockIdx.x * 64;
  const int wm = wave & 1, wn = wave >> 1;
  float4v acc[2][2];
#pragma unroll
  for (int i = 0; i < 2; i++)
#pragma unroll
    for (int j = 0; j < 2; j++) acc[i][j] = (float4v){0.f, 0.f, 0.f, 0.f};
  float4 pf0[2], pf1[2];
  auto ldu = [&](int j, int k0) {
    int u = tid + j * 256;
    const float4* p;
    if (u < 256) { int row = u >> 2, q = u & 3;
      p = (const float4*)(t1 + (size_t)(m0 + row) * 96 + k0 + q * 8);
    } else { int v = u - 256; int row = v >> 2, q = v & 3;
      p = (const float4*)(WD2 + (size_t)(n0 + row) * DD + k0 + q * 8);
    }
    pf0[j] = p[0]; pf1[j] = p[1];
  };
  auto stu = [&](int j) {
    int u = tid + j * 256;
    short8 s = pack8(pf0[j], pf1[j]);
    if (u < 256) { int row = u >> 2, q = u & 3; *(short8*)&As[row * 40 + q * 8] = s; }
    else { int v = u - 256; int row = v >> 2, q = v & 3; *(short8*)&Bs[row * 40 + q * 8] = s; }
  };
  ldu(0, 0); ldu(1, 0);
  for (int k0 = 0; k0 < DD; k0 += 32) {
    stu(0); stu(1);
    __syncthreads();
    if (k0 + 32 < DD) { ldu(0, k0 + 32); ldu(1, k0 + 32); }
    short8 afr[2], bfr[2];
#pragma unroll
    for (int mi = 0; mi < 2; mi++)
      afr[mi] = *(const short8*)&As[(wm * 32 + mi * 16 + r16) * 40 + quad * 8];
#pragma unroll
    for (int ni = 0; ni < 2; ni++)
      bfr[ni] = *(const short8*)&Bs[(wn * 32 + ni * 16 + r16) * 40 + quad * 8];
#pragma unroll
    for (int mi = 0; mi < 2; mi++)
#pragma unroll
      for (int ni = 0; ni < 2; ni++)
        acc[mi][ni] = __builtin_amdgcn_mfma_f32_16x16x32_bf16(afr[mi], bfr[ni], acc[mi][ni], 0, 0, 0);
    __syncthreads();
  }
#pragma unroll
  for (int mi = 0; mi < 2; mi++)
#pragma unroll
    for (int ni = 0; ni < 2; ni++) {
      int gn = n0 + wn * 32 + ni * 16 + r16;
      float dvn = Dv[gn];
#pragma unroll
      for (int r = 0; r < 4; r++) {
        int gm = m0 + wm * 32 + mi * 16 + quad * 4 + r;
        float v = acc[mi][ni][r] + dvn;
        v = fmaxf(v, 0.f) + log1pf(expf(-fabsf(v)));   // stable softplus
        dltT[(size_t)gn * NROW + gm] = v;              // transposed, 16B runs
      }
    }
}

// ---------------------------------------------------------------------------
// Fused selective scan. R17: delta read from dltT again (fusion reverted);
// 512 thr, segmented phase B (B1 local 16-scan + B2 8-segment combine);
// carry rows remapped combo = dd*16+s (pad 129) -> every LDS access in
// phases A/B/C is <=2 lanes/bank (was 4-way on A/C stores; 1.57M conflicts).
// ---------------------------------------------------------------------------
__global__ __launch_bounds__(512, 2)
void scan_fused_k(const float* __restrict__ xt, const float* __restrict__ dltT,
                  const float* __restrict__ pall, const float* __restrict__ A,
                  const float* __restrict__ Dv, const short* __restrict__ gt,
                  short* __restrict__ soutb) {
  __shared__ float Pl[DS * SD][SC + 1];   // 33024 B
  __shared__ float Hl[DS * SD][SC + 1];   // 33024 B
  __shared__ float Ps[DS * SD][NSEG + 1]; //  2304 B
  __shared__ float Hs[DS * SD][NSEG + 1]; //  2304 B
  const int blk = blockIdx.x;
  const int b   = blk >> 8;                // DM/SD = 256 blocks per batch
  const int d0  = (blk & 255) * SD;
  const int dd  = threadIdx.x & (SD - 1);
  const int c   = threadIdx.x >> 2;        // 0..127
  const int d   = d0 + dd;

  float e[DS];
#pragma unroll
  for (int s = 0; s < DS; s++) e[s] = expf(-A[d * DS + s]);

  const int nbase = b * L_ + c * SLC;
  const float* xrow = xt   + (size_t)d * NROW;
  const float* drow = dltT + (size_t)d * NROW;
  const short* grow = gt   + (size_t)d * NROW;

  // ---- phase A: local chunk scan, quad-batched ------------------------
  float h[DS];
#pragma unroll
  for (int s = 0; s < DS; s++) h[s] = 0.f;
  float pdl = 1.f;
#pragma unroll
  for (int q = 0; q < SLC / 4; q++) {
    const int n = nbase + q * 4;
    float4 x4 = *(const float4*)(xrow + n);
    float4 d4 = *(const float4*)(drow + n);
    float4 bq[4][4];
#pragma unroll
    for (int t = 0; t < 4; t++) {
      const float4* pp = (const float4*)(pall + (size_t)(n + t) * 96);
      bq[t][0] = pp[0]; bq[t][1] = pp[1]; bq[t][2] = pp[2]; bq[t][3] = pp[3];
    }
#pragma unroll
    for (int t = 0; t < 4; t++) {
      float dl = (&d4.x)[t], xv = (&x4.x)[t];
      float dx = dl * xv;
      pdl *= dl;
      float bmv[DS] = { bq[t][0].x, bq[t][0].y, bq[t][0].z, bq[t][0].w,
                        bq[t][1].x, bq[t][1].y, bq[t][1].z, bq[t][1].w,
                        bq[t][2].x, bq[t][2].y, bq[t][2].z, bq[t][2].w,
                        bq[t][3].x, bq[t][3].y, bq[t][3].z, bq[t][3].w };
#pragma unroll
      for (int s = 0; s < DS; s++)
        h[s] = (e[s] * dl) * h[s] + bmv[s] * dx;
    }
  }
#pragma unroll
  for (int s = 0; s < DS; s++) {
    float e2 = e[s] * e[s], e4 = e2 * e2, e8 = e4 * e4;   // e^SLC, SLC=8
    Pl[dd * DS + s][c] = e8 * pdl;
    Hl[dd * DS + s][c] = h[s];
  }
  __syncthreads();

  // ---- phase B1: 512 thr, 16-chunk local exclusive scans --------------
  {
    const int seg = threadIdx.x >> 6;       // 0..7
    const int cmb = threadIdx.x & 63;       // row (opaque combo index)
    float* Prow = &Pl[cmb][0];
    float* Hrow = &Hl[cmb][0];
    float Pa = 1.f, Ha = 0.f;
#pragma unroll
    for (int i = 0; i < SC / NSEG; i++) {
      int c2 = seg * (SC / NSEG) + i;
      float p = Prow[c2], hh = Hrow[c2];
      Prow[c2] = Pa;                        // local exclusive prefix product
      Hrow[c2] = Ha;                        // local exclusive prefix H
      Ha = p * Ha + hh;
      Pa *= p;
    }
    Ps[cmb][seg] = Pa;
    Hs[cmb][seg] = Ha;
  }
  __syncthreads();

  // ---- phase B2: 64 thr, serial combine of 8 segment carries ----------
  if (threadIdx.x < DS * SD) {
    float* Pr = &Ps[threadIdx.x][0];
    float* Hr = &Hs[threadIdx.x][0];
    float H = 0.f;
#pragma unroll
    for (int g = 0; g < NSEG; g++) {
      float p = Pr[g], hh = Hr[g];
      Hr[g] = H;                            // segment-exclusive carry-in
      H = p * H + hh;
    }
  }
  __syncthreads();

  // ---- phase C: replay with fused epilogue, quad-batched --------------
  {
    const int g = c >> 4;
#pragma unroll
    for (int s = 0; s < DS; s++)
      h[s] = Pl[dd * DS + s][c] * Hs[dd * DS + s][g] + Hl[dd * DS + s][c];
  }
  const float Dd = Dv[d];
#pragma unroll
  for (int q = 0; q < SLC / 4; q++) {
    const int n = nbase + q * 4;
    float4 x4 = *(const float4*)(xrow + n);
    float4 d4 = *(const float4*)(drow + n);
    short4v g4 = *(const short4v*)(grow + n);
    float4 bq[4][4], cq[4][4];
#pragma unroll
    for (int t = 0; t < 4; t++) {
      const float4* pp = (const float4*)(pall + (size_t)(n + t) * 96);
      bq[t][0] = pp[0]; bq[t][1] = pp[1]; bq[t][2] = pp[2]; bq[t][3] = pp[3];
      cq[t][0] = pp[4]; cq[t][1] = pp[5]; cq[t][2] = pp[6]; cq[t][3] = pp[7];
    }
#pragma unroll
    for (int t = 0; t < 4; t++) {
      float dl = (&d4.x)[t], xv = (&x4.x)[t];
      float dx = dl * xv;
      float bmv[DS] = { bq[t][0].x, bq[t][0].y, bq[t][0].z, bq[t][0].w,
                        bq[t][1].x, bq[t][1].y, bq[t][1].z, bq[t][1].w,
                        bq[t][2].x, bq[t][2].y, bq[t][2].z, bq[t][2].w,
                        bq[t][3].x, bq[t][3].y, bq[t][3].z, bq[t][3].w };
      float cmv[DS] = { cq[t][0].x, cq[t][0].y, cq[t][0].z, cq[t][0].w,
                        cq[t][1].x, cq[t][1].y, cq[t][1].z, cq[t][1].w,
                        cq[t][2].x, cq[t][2].y, cq[t][2].z, cq[t][2].w,
                        cq[t][3].x, cq[t][3].y, cq[t][3].z, cq[t][3].w };
      float y = 0.f;
#pragma unroll
      for (int s = 0; s < DS; s++) {
        h[s] = (e[s] * dl) * h[s] + bmv[s] * dx;
        y += h[s] * cmv[s];
      }
      y += Dd * xv;
      float gg = bf2f(g4[t]);
      soutb[(size_t)(n + t) * DM + d] = f2bf1(y * silu_f(gg));
    }
  }
}

// ---------------------------------------------------------------------------
// GEMM2: out[2048,512] = sout(bf16)[2048,1024] . Wout[512,1024]^T
// BM=64, BN=32 -> 512 blocks. 256 thr = 4 waves (2x2), wave tile 32x16.
// ---------------------------------------------------------------------------
__global__ __launch_bounds__(256)
void gemm2_k(const short* __restrict__ soutb, const float* __restrict__ Wout,
             float* __restrict__ out) {
  __shared__ short As[64 * 40];
  __shared__ short Bs[32 * 40];
  const int tid  = threadIdx.x;
  const int lane = tid & 63;
  const int wave = tid >> 6;
  const int r16  = lane & 15;
  const int quad = lane >> 4;
  const int m0 = blockIdx.y * 64;
  const int n0 = blockIdx.x * 32;
  const int wm = wave & 1, wn = wave >> 1;
  float4v acc[2];
  acc[0] = (float4v){0.f, 0.f, 0.f, 0.f};
  acc[1] = (float4v){0.f, 0.f, 0.f, 0.f};
  short8 pa;
  float4 pf0, pf1;
  auto ldu = [&](int k0) {
    {
      int row = tid >> 2, q = tid & 3;
      pa = *(const short8*)(soutb + (size_t)(m0 + row) * DM + k0 + q * 8);
    }
    if (tid < 128) {
      int row = tid >> 2, q = tid & 3;
      const float4* p = (const float4*)(Wout + (size_t)(n0 + row) * DM + k0 + q * 8);
      pf0 = p[0]; pf1 = p[1];
    }
  };
  auto stu = [&]() {
    { int row = tid >> 2, q = tid & 3; *(short8*)&As[row * 40 + q * 8] = pa; }
    if (tid < 128) { int row = tid >> 2, q = tid & 3; *(short8*)&Bs[row * 40 + q * 8] = pack8(pf0, pf1); }
  };
  ldu(0);
  for (int k0 = 0; k0 < DM; k0 += 32) {
    stu();
    __syncthreads();
    if (k0 + 32 < DM) ldu(k0 + 32);
    short8 afr[2], bfr;
    afr[0] = *(const short8*)&As[(wm * 32 + r16) * 40 + quad * 8];
    afr[1] = *(const short8*)&As[(wm * 32 + 16 + r16) * 40 + quad * 8];
    bfr    = *(const short8*)&Bs[(wn * 16 + r16) * 40 + quad * 8];
    acc[0] = __builtin_amdgcn_mfma_f32_16x16x32_bf16(afr[0], bfr, acc[0], 0, 0, 0);
    acc[1] = __builtin_amdgcn_mfma_f32_16x16x32_bf16(afr[1], bfr, acc[1], 0, 0, 0);
    __syncthreads();
  }
#pragma unroll
  for (int mi = 0; mi < 2; mi++)
#pragma unroll
    for (int r = 0; r < 4; r++)
      out[(size_t)(m0 + wm * 32 + mi * 16 + quad * 4 + r) * DIN + n0 + wn * 16 + r16] = acc[mi][r];
}

// ---------------------------------------------------------------------------
extern "C" void kernel_launch(void* const* d_in, const int* in_sizes, int n_in,
                              void* d_out, int out_size, void* d_ws, size_t ws_size,
                              hipStream_t stream) {
  const float* seq  = (const float*)d_in[0];
  const float* Win  = (const float*)d_in[1];
  const float* Wout = (const float*)d_in[2];
  const float* WB   = (const float*)d_in[3];
  const float* WC   = (const float*)d_in[4];
  const float* WD1  = (const float*)d_in[5];
  const float* WD2  = (const float*)d_in[6];
  const float* cw   = (const float*)d_in[7];
  const float* cb   = (const float*)d_in[8];
  const float* A    = (const float*)d_in[9];
  const float* Dv   = (const float*)d_in[10];
  float* out = (float*)d_out;

  float* ws = (float*)d_ws;
  __hip_bfloat16* ab = (__hip_bfloat16*)ws;       // 2048*2048 bf16
  float* xt   = ws   + 2097152;                   // 1024*2048 f32  (x transposed)
  short* gt   = (short*)(xt + 2097152);           // 1024*2048 bf16 (gate transposed)
  float* dltT = (float*)(gt + 2097152);           // 1024*2048 f32  (delta transposed)
  float* pall = dltT + 2097152;                   // 2048*96 f32 (Bm|Cm|t1)
  short* soutb = (short*)(pall + 196608);         // 2048*1024 bf16
  // total ~35 MB (proven budget 47)
  float* t1   = pall + 32;                        // t1 rows at col 32 (ld 96)

  gemm1_k<<<dim3(32, 32), 256, 0, stream>>>(seq, Win, ab, pall);
  convproj_k<<<1280, 256, 0, stream>>>(ab, cw, cb, WB, WC, WD1, xt, gt, pall);
  delta_k<<<dim3(16, 32), 256, 0, stream>>>(t1, WD2, Dv, dltT);
  scan_fused_k<<<B_ * (DM / SD), 512, 0, stream>>>(xt, dltT, pall, A, Dv, gt, soutb);
  gemm2_k<<<dim3(16, 32), 256, 0, stream>>>(soutb, Wout, out);
}

// Round 5
// 161.050 us; speedup vs baseline: 1.8399x; 1.0064x over previous
//
#include <hip/hip_runtime.h>
#include <hip/hip_bf16.h>

typedef short short8 __attribute__((ext_vector_type(8)));
typedef short short4v __attribute__((ext_vector_type(4)));
typedef float float4v __attribute__((ext_vector_type(4)));

#define B_   2
#define L_   1024
#define DIN  512
#define DM   1024
#define DS   16
#define DD   64
#define KER_ 4
#define NROW (B_*L_)     // 2048

// scan geometry: block = (b, 4 d-lanes); 128 chunks x 8 steps = L, 512 thr
#define SD   4
#define SC   128
#define SLC  8
#define NSEG 8           // phase-B segments (SC/16)

__device__ __forceinline__ float silu_f(float v){ return v / (1.f + expf(-v)); }

__device__ __forceinline__ short2 f2bf2(float a, float b) {
  __hip_bfloat162 h = __float22bfloat162_rn(float2{a, b});
  union { __hip_bfloat162 h; short2 s; } u; u.h = h; return u.s;
}
__device__ __forceinline__ short f2bf1(float a) {
  __hip_bfloat16 h = __float2bfloat16(a);
  union { __hip_bfloat16 h; short s; } u; u.h = h; return u.s;
}
__device__ __forceinline__ short8 pack8(const float4& x0, const float4& x1) {
  short2 s0 = f2bf2(x0.x, x0.y), s1 = f2bf2(x0.z, x0.w);
  short2 s2 = f2bf2(x1.x, x1.y), s3 = f2bf2(x1.z, x1.w);
  return short8{ s0.x, s0.y, s1.x, s1.y, s2.x, s2.y, s3.x, s3.y };
}
__device__ __forceinline__ float bf2f(short s) {
  union { unsigned u; float f; } v; v.u = ((unsigned)(unsigned short)s) << 16; return v.f;
}

// ---------------------------------------------------------------------------
// GEMM1 (R18): ab[2048,2048](bf16) = seq[2048,512] . Win[2048,512]^T
// 128x128 tile, 512 thr = 8 waves (2m x 4n), wave tile 64x32, BK=32,
// reg-prefetch f32->bf16 pack staging. Grid 16x16 = 256 blocks = 1/CU.
// Also zeroes pall (2 floats/thread over 256 blocks x 512 thr).
// ---------------------------------------------------------------------------
__global__ __launch_bounds__(512)
void gemm1_k(const float* __restrict__ seq, const float* __restrict__ Win,
             __hip_bfloat16* __restrict__ ab, float* __restrict__ pall) {
  __shared__ short As[128 * 40];
  __shared__ short Bs[128 * 40];
  const int tid  = threadIdx.x;
  // fold-in: zero pall (196608 floats over 256 blocks x 512 thr x 2)
  {
    int zi = (blockIdx.y * 16 + blockIdx.x) * 1024 + tid * 2;
    if (zi < NROW * 96) { pall[zi] = 0.f; pall[zi + 1] = 0.f; }
  }
  const int lane = tid & 63;
  const int wave = tid >> 6;        // 0..7
  const int r16  = lane & 15;
  const int quad = lane >> 4;
  const int m0 = blockIdx.y * 128;
  const int n0 = blockIdx.x * 128;
  const int wm = wave & 1;          // 0..1 -> 64-row half
  const int wn = wave >> 1;         // 0..3 -> 32-col quarter
  float4v acc[4][2];
#pragma unroll
  for (int i = 0; i < 4; i++)
#pragma unroll
    for (int j = 0; j < 2; j++) acc[i][j] = (float4v){0.f, 0.f, 0.f, 0.f};
  const int row = tid >> 2, q = tid & 3;
  float4 pfA0, pfA1, pfB0, pfB1;
  auto ldu = [&](int k0) {
    const float4* pa = (const float4*)(seq + (size_t)(m0 + row) * DIN + k0 + q * 8);
    pfA0 = pa[0]; pfA1 = pa[1];
    const float4* pb = (const float4*)(Win + (size_t)(n0 + row) * DIN + k0 + q * 8);
    pfB0 = pb[0]; pfB1 = pb[1];
  };
  auto stu = [&]() {
    *(short8*)&As[row * 40 + q * 8] = pack8(pfA0, pfA1);
    *(short8*)&Bs[row * 40 + q * 8] = pack8(pfB0, pfB1);
  };
  ldu(0);
  for (int k0 = 0; k0 < DIN; k0 += 32) {
    stu();
    __syncthreads();
    if (k0 + 32 < DIN) ldu(k0 + 32);
    short8 afr[4], bfr[2];
#pragma unroll
    for (int mi = 0; mi < 4; mi++)
      afr[mi] = *(const short8*)&As[(wm * 64 + mi * 16 + r16) * 40 + quad * 8];
#pragma unroll
    for (int ni = 0; ni < 2; ni++)
      bfr[ni] = *(const short8*)&Bs[(wn * 32 + ni * 16 + r16) * 40 + quad * 8];
#pragma unroll
    for (int mi = 0; mi < 4; mi++)
#pragma unroll
      for (int ni = 0; ni < 2; ni++)
        acc[mi][ni] = __builtin_amdgcn_mfma_f32_16x16x32_bf16(afr[mi], bfr[ni], acc[mi][ni], 0, 0, 0);
    __syncthreads();
  }
#pragma unroll
  for (int mi = 0; mi < 4; mi++)
#pragma unroll
    for (int ni = 0; ni < 2; ni++) {
      int gn = n0 + wn * 32 + ni * 16 + r16;
#pragma unroll
      for (int r = 0; r < 4; r++) {
        int gm = m0 + wm * 64 + mi * 16 + quad * 4 + r;
        ab[(size_t)gm * (2 * DM) + gn] = __float2bfloat16(acc[mi][ni][r]);
      }
    }
}

// ---------------------------------------------------------------------------
// convT + proj merged (independent consumers of ab; block-range split).
// blk < 1024: convT tile -> xT (f32, silu(conv)) / gT (bf16 gate transpose).
//   R18: tile pitch 74->72 shorts (16B-aligned rows) and consumer reads
//   vectorized short8 (8 ds_read_b128/thread instead of 64 ds_read_u16).
// blk >= 1024: proj split-K block -> pall atomicAdd (pall zeroed by gemm1).
// ---------------------------------------------------------------------------
__global__ __launch_bounds__(256)
void convproj_k(const __hip_bfloat16* __restrict__ ab, const float* __restrict__ cw,
                const float* __restrict__ cb, const float* __restrict__ WB,
                const float* __restrict__ WC, const float* __restrict__ WD1,
                float* __restrict__ xt, short* __restrict__ gt,
                float* __restrict__ pall) {
  __shared__ char smraw[12800];
  const int blk = blockIdx.x;
  const int tid = threadIdx.x;

  if (blk < 1024) {
    // ---------------- convT (pitch-72, vectorized reads) ----------------
    short* tile = (short*)smraw;               // 67*72 shorts = 9648 B
    const int n0 = (blk & 31) * 64;
    const int d0 = (blk >> 5) * 64;            // 0..2047
    const int l0 = n0 & (L_ - 1);
    for (int u = tid; u < 67 * 8; u += 256) {
      int r = u >> 3, c8 = u & 7;
      int l = l0 - 3 + r;
      short8 v = short8{0, 0, 0, 0, 0, 0, 0, 0};
      if (l >= 0 && r < 67)
        v = *(const short8*)(ab + (size_t)(n0 - l0 + l) * (2 * DM) + d0 + c8 * 8);
      *(short8*)&tile[r * 72 + c8 * 8] = v;
    }
    __syncthreads();
    const int i  = tid & 63;
    const int dl = tid >> 6;                   // 0..3 -> 16-d group
    if (d0 < DM) {
#pragma unroll
      for (int p8 = 0; p8 < 2; p8++) {
        const int dc0 = dl * 16 + p8 * 8;
        short8 t0 = *(const short8*)&tile[(i + 0) * 72 + dc0];
        short8 t1 = *(const short8*)&tile[(i + 1) * 72 + dc0];
        short8 t2 = *(const short8*)&tile[(i + 2) * 72 + dc0];
        short8 t3 = *(const short8*)&tile[(i + 3) * 72 + dc0];
#pragma unroll
        for (int e = 0; e < 8; e++) {
          int d = d0 + dc0 + e;
          float4 w = *(const float4*)(cw + d * 4);
          float a = cb[d];
          a += bf2f(t0[e]) * w.x;
          a += bf2f(t1[e]) * w.y;
          a += bf2f(t2[e]) * w.z;
          a += bf2f(t3[e]) * w.w;
          xt[(size_t)d * NROW + n0 + i] = silu_f(a);
        }
      }
    } else {
#pragma unroll
      for (int p8 = 0; p8 < 2; p8++) {
        const int dc0 = dl * 16 + p8 * 8;
        short8 v = *(const short8*)&tile[(i + 3) * 72 + dc0];
#pragma unroll
        for (int e = 0; e < 8; e++)
          gt[(size_t)(d0 - DM + dc0 + e) * NROW + n0 + i] = v[e];
      }
    }
    return;
  }

  // ---------------- proj (verbatim R13 body) ----------------------------
  short* As = (short*)smraw;                   // 64*40
  short* Bs = As + 64 * 40;                    // 96*40  (total 12800 B)
  const int b2   = blk - 1024;                 // 0..255
  const int lane = tid & 63;
  const int wave = tid >> 6;
  const int r16  = lane & 15;
  const int quad = lane >> 4;
  const int m0   = (b2 & 31) * 64;
  const int kbeg = (b2 >> 5) * 128;
  float4v acc[6];
#pragma unroll
  for (int i = 0; i < 6; i++) acc[i] = (float4v){0.f, 0.f, 0.f, 0.f};

  short8 ta[KER_];
  float4 pf0[2], pf1[2];
  const int arow = tid >> 2, aq = tid & 3;
  const int an = m0 + arow, al = an & (L_ - 1), abq = an >> 10;

  auto ldu_a = [&](int k0) {
#pragma unroll
    for (int t = 0; t < KER_; t++) {
      int ll = al - (KER_ - 1) + t;
      if (ll >= 0)
        ta[t] = *(const short8*)(ab + (size_t)(abq * L_ + ll) * (2 * DM) + k0 + aq * 8);
      else
        ta[t] = short8{0, 0, 0, 0, 0, 0, 0, 0};
    }
  };
  auto stu_a = [&](int k0) {
    float r8[8];
#pragma unroll
    for (int e = 0; e < 8; e++) {
      int d = k0 + aq * 8 + e;
      float4 w = *(const float4*)(cw + d * 4);
      float a = cb[d];
      a += bf2f(ta[0][e]) * w.x;
      a += bf2f(ta[1][e]) * w.y;
      a += bf2f(ta[2][e]) * w.z;
      a += bf2f(ta[3][e]) * w.w;
      r8[e] = silu_f(a);
    }
    *(short8*)&As[arow * 40 + aq * 8] =
        pack8(float4{r8[0], r8[1], r8[2], r8[3]}, float4{r8[4], r8[5], r8[6], r8[7]});
  };
  auto ldu_b = [&](int j, int k0) {
    int u = tid + j * 256;
    if (u >= 640) return;
    int v = u - 256, row = v >> 2, q = v & 3;
    const float* bp = (row < 16) ? (WB + (size_t)row * DM)
                    : (row < 32) ? (WC + (size_t)(row - 16) * DM)
                                 : (WD1 + (size_t)(row - 32) * DM);
    const float4* p = (const float4*)(bp + k0 + q * 8);
    pf0[j - 1] = p[0]; pf1[j - 1] = p[1];
  };
  auto stu_b = [&](int j) {
    int u = tid + j * 256;
    if (u >= 640) return;
    int v = u - 256, row = v >> 2, q = v & 3;
    *(short8*)&Bs[row * 40 + q * 8] = pack8(pf0[j - 1], pf1[j - 1]);
  };

  ldu_a(kbeg); ldu_b(1, kbeg); ldu_b(2, kbeg);
  for (int k0 = kbeg; k0 < kbeg + 128; k0 += 32) {
    stu_a(k0); stu_b(1); stu_b(2);
    __syncthreads();
    if (k0 + 32 < kbeg + 128) { ldu_a(k0 + 32); ldu_b(1, k0 + 32); ldu_b(2, k0 + 32); }
    short8 afr = *(const short8*)&As[(wave * 16 + r16) * 40 + quad * 8];
#pragma unroll
    for (int ni = 0; ni < 6; ni++) {
      short8 bfr = *(const short8*)&Bs[(ni * 16 + r16) * 40 + quad * 8];
      acc[ni] = __builtin_amdgcn_mfma_f32_16x16x32_bf16(afr, bfr, acc[ni], 0, 0, 0);
    }
    __syncthreads();
  }
#pragma unroll
  for (int ni = 0; ni < 6; ni++) {
    int gn = ni * 16 + r16;
#pragma unroll
    for (int r = 0; r < 4; r++) {
      int gm = m0 + wave * 16 + quad * 4 + r;
      atomicAdd(&pall[(size_t)gm * 96 + gn], acc[ni][r]);
    }
  }
}

// ---------------------------------------------------------------------------
// delta: dltT[1024,2048] = softplus(t1 . WD2^T + Dv)^T  (transposed store)
// ---------------------------------------------------------------------------
__global__ __launch_bounds__(256)
void delta_k(const float* __restrict__ t1, const float* __restrict__ WD2,
             const float* __restrict__ Dv, float* __restrict__ dltT) {
  __shared__ short As[64 * 40];
  __shared__ short Bs[64 * 40];
  const int tid  = threadIdx.x;
  const int lane = tid & 63;
  const int wave = tid >> 6;
  const int r16  = lane & 15;
  const int quad = lane >> 4;
  const int m0 = blockIdx.y * 64;
  const int n0 = blockIdx.x * 64;
  const int wm = wave & 1, wn = wave >> 1;
  float4v acc[2][2];
#pragma unroll
  for (int i = 0; i < 2; i++)
#pragma unroll
    for (int j = 0; j < 2; j++) acc[i][j] = (float4v){0.f, 0.f, 0.f, 0.f};
  float4 pf0[2], pf1[2];
  auto ldu = [&](int j, int k0) {
    int u = tid + j * 256;
    const float4* p;
    if (u < 256) { int row = u >> 2, q = u & 3;
      p = (const float4*)(t1 + (size_t)(m0 + row) * 96 + k0 + q * 8);
    } else { int v = u - 256; int row = v >> 2, q = v & 3;
      p = (const float4*)(WD2 + (size_t)(n0 + row) * DD + k0 + q * 8);
    }
    pf0[j] = p[0]; pf1[j] = p[1];
  };
  auto stu = [&](int j) {
    int u = tid + j * 256;
    short8 s = pack8(pf0[j], pf1[j]);
    if (u < 256) { int row = u >> 2, q = u & 3; *(short8*)&As[row * 40 + q * 8] = s; }
    else { int v = u - 256; int row = v >> 2, q = v & 3; *(short8*)&Bs[row * 40 + q * 8] = s; }
  };
  ldu(0, 0); ldu(1, 0);
  for (int k0 = 0; k0 < DD; k0 += 32) {
    stu(0); stu(1);
    __syncthreads();
    if (k0 + 32 < DD) { ldu(0, k0 + 32); ldu(1, k0 + 32); }
    short8 afr[2], bfr[2];
#pragma unroll
    for (int mi = 0; mi < 2; mi++)
      afr[mi] = *(const short8*)&As[(wm * 32 + mi * 16 + r16) * 40 + quad * 8];
#pragma unroll
    for (int ni = 0; ni < 2; ni++)
      bfr[ni] = *(const short8*)&Bs[(wn * 32 + ni * 16 + r16) * 40 + quad * 8];
#pragma unroll
    for (int mi = 0; mi < 2; mi++)
#pragma unroll
      for (int ni = 0; ni < 2; ni++)
        acc[mi][ni] = __builtin_amdgcn_mfma_f32_16x16x32_bf16(afr[mi], bfr[ni], acc[mi][ni], 0, 0, 0);
    __syncthreads();
  }
#pragma unroll
  for (int mi = 0; mi < 2; mi++)
#pragma unroll
    for (int ni = 0; ni < 2; ni++) {
      int gn = n0 + wn * 32 + ni * 16 + r16;
      float dvn = Dv[gn];
#pragma unroll
      for (int r = 0; r < 4; r++) {
        int gm = m0 + wm * 32 + mi * 16 + quad * 4 + r;
        float v = acc[mi][ni][r] + dvn;
        v = fmaxf(v, 0.f) + log1pf(expf(-fabsf(v)));   // stable softplus
        dltT[(size_t)gn * NROW + gm] = v;              // transposed, 16B runs
      }
    }
}

// ---------------------------------------------------------------------------
// Fused selective scan (verbatim R17: conflict-free combo = dd*16+s rows,
// segmented phase B, 512 thr, launch_bounds (512,2)).
// ---------------------------------------------------------------------------
__global__ __launch_bounds__(512, 2)
void scan_fused_k(const float* __restrict__ xt, const float* __restrict__ dltT,
                  const float* __restrict__ pall, const float* __restrict__ A,
                  const float* __restrict__ Dv, const short* __restrict__ gt,
                  short* __restrict__ soutb) {
  __shared__ float Pl[DS * SD][SC + 1];   // 33024 B
  __shared__ float Hl[DS * SD][SC + 1];   // 33024 B
  __shared__ float Ps[DS * SD][NSEG + 1]; //  2304 B
  __shared__ float Hs[DS * SD][NSEG + 1]; //  2304 B
  const int blk = blockIdx.x;
  const int b   = blk >> 8;                // DM/SD = 256 blocks per batch
  const int d0  = (blk & 255) * SD;
  const int dd  = threadIdx.x & (SD - 1);
  const int c   = threadIdx.x >> 2;        // 0..127
  const int d   = d0 + dd;

  float e[DS];
#pragma unroll
  for (int s = 0; s < DS; s++) e[s] = expf(-A[d * DS + s]);

  const int nbase = b * L_ + c * SLC;
  const float* xrow = xt   + (size_t)d * NROW;
  const float* drow = dltT + (size_t)d * NROW;
  const short* grow = gt   + (size_t)d * NROW;

  // ---- phase A: local chunk scan, quad-batched ------------------------
  float h[DS];
#pragma unroll
  for (int s = 0; s < DS; s++) h[s] = 0.f;
  float pdl = 1.f;
#pragma unroll
  for (int q = 0; q < SLC / 4; q++) {
    const int n = nbase + q * 4;
    float4 x4 = *(const float4*)(xrow + n);
    float4 d4 = *(const float4*)(drow + n);
    float4 bq[4][4];
#pragma unroll
    for (int t = 0; t < 4; t++) {
      const float4* pp = (const float4*)(pall + (size_t)(n + t) * 96);
      bq[t][0] = pp[0]; bq[t][1] = pp[1]; bq[t][2] = pp[2]; bq[t][3] = pp[3];
    }
#pragma unroll
    for (int t = 0; t < 4; t++) {
      float dl = (&d4.x)[t], xv = (&x4.x)[t];
      float dx = dl * xv;
      pdl *= dl;
      float bmv[DS] = { bq[t][0].x, bq[t][0].y, bq[t][0].z, bq[t][0].w,
                        bq[t][1].x, bq[t][1].y, bq[t][1].z, bq[t][1].w,
                        bq[t][2].x, bq[t][2].y, bq[t][2].z, bq[t][2].w,
                        bq[t][3].x, bq[t][3].y, bq[t][3].z, bq[t][3].w };
#pragma unroll
      for (int s = 0; s < DS; s++)
        h[s] = (e[s] * dl) * h[s] + bmv[s] * dx;
    }
  }
#pragma unroll
  for (int s = 0; s < DS; s++) {
    float e2 = e[s] * e[s], e4 = e2 * e2, e8 = e4 * e4;   // e^SLC, SLC=8
    Pl[dd * DS + s][c] = e8 * pdl;
    Hl[dd * DS + s][c] = h[s];
  }
  __syncthreads();

  // ---- phase B1: 512 thr, 16-chunk local exclusive scans --------------
  {
    const int seg = threadIdx.x >> 6;       // 0..7
    const int cmb = threadIdx.x & 63;       // row (opaque combo index)
    float* Prow = &Pl[cmb][0];
    float* Hrow = &Hl[cmb][0];
    float Pa = 1.f, Ha = 0.f;
#pragma unroll
    for (int i = 0; i < SC / NSEG; i++) {
      int c2 = seg * (SC / NSEG) + i;
      float p = Prow[c2], hh = Hrow[c2];
      Prow[c2] = Pa;                        // local exclusive prefix product
      Hrow[c2] = Ha;                        // local exclusive prefix H
      Ha = p * Ha + hh;
      Pa *= p;
    }
    Ps[cmb][seg] = Pa;
    Hs[cmb][seg] = Ha;
  }
  __syncthreads();

  // ---- phase B2: 64 thr, serial combine of 8 segment carries ----------
  if (threadIdx.x < DS * SD) {
    float* Pr = &Ps[threadIdx.x][0];
    float* Hr = &Hs[threadIdx.x][0];
    float H = 0.f;
#pragma unroll
    for (int g = 0; g < NSEG; g++) {
      float p = Pr[g], hh = Hr[g];
      Hr[g] = H;                            // segment-exclusive carry-in
      H = p * H + hh;
    }
  }
  __syncthreads();

  // ---- phase C: replay with fused epilogue, quad-batched --------------
  {
    const int g = c >> 4;
#pragma unroll
    for (int s = 0; s < DS; s++)
      h[s] = Pl[dd * DS + s][c] * Hs[dd * DS + s][g] + Hl[dd * DS + s][c];
  }
  const float Dd = Dv[d];
#pragma unroll
  for (int q = 0; q < SLC / 4; q++) {
    const int n = nbase + q * 4;
    float4 x4 = *(const float4*)(xrow + n);
    float4 d4 = *(const float4*)(drow + n);
    short4v g4 = *(const short4v*)(grow + n);
    float4 bq[4][4], cq[4][4];
#pragma unroll
    for (int t = 0; t < 4; t++) {
      const float4* pp = (const float4*)(pall + (size_t)(n + t) * 96);
      bq[t][0] = pp[0]; bq[t][1] = pp[1]; bq[t][2] = pp[2]; bq[t][3] = pp[3];
      cq[t][0] = pp[4]; cq[t][1] = pp[5]; cq[t][2] = pp[6]; cq[t][3] = pp[7];
    }
#pragma unroll
    for (int t = 0; t < 4; t++) {
      float dl = (&d4.x)[t], xv = (&x4.x)[t];
      float dx = dl * xv;
      float bmv[DS] = { bq[t][0].x, bq[t][0].y, bq[t][0].z, bq[t][0].w,
                        bq[t][1].x, bq[t][1].y, bq[t][1].z, bq[t][1].w,
                        bq[t][2].x, bq[t][2].y, bq[t][2].z, bq[t][2].w,
                        bq[t][3].x, bq[t][3].y, bq[t][3].z, bq[t][3].w };
      float cmv[DS] = { cq[t][0].x, cq[t][0].y, cq[t][0].z, cq[t][0].w,
                        cq[t][1].x, cq[t][1].y, cq[t][1].z, cq[t][1].w,
                        cq[t][2].x, cq[t][2].y, cq[t][2].z, cq[t][2].w,
                        cq[t][3].x, cq[t][3].y, cq[t][3].z, cq[t][3].w };
      float y = 0.f;
#pragma unroll
      for (int s = 0; s < DS; s++) {
        h[s] = (e[s] * dl) * h[s] + bmv[s] * dx;
        y += h[s] * cmv[s];
      }
      y += Dd * xv;
      float gg = bf2f(g4[t]);
      soutb[(size_t)(n + t) * DM + d] = f2bf1(y * silu_f(gg));
    }
  }
}

// ---------------------------------------------------------------------------
// GEMM2: out[2048,512] = sout(bf16)[2048,1024] . Wout[512,1024]^T
// BM=64, BN=32 -> 512 blocks. 256 thr = 4 waves (2x2), wave tile 32x16.
// ---------------------------------------------------------------------------
__global__ __launch_bounds__(256)
void gemm2_k(const short* __restrict__ soutb, const float* __restrict__ Wout,
             float* __restrict__ out) {
  __shared__ short As[64 * 40];
  __shared__ short Bs[32 * 40];
  const int tid  = threadIdx.x;
  const int lane = tid & 63;
  const int wave = tid >> 6;
  const int r16  = lane & 15;
  const int quad = lane >> 4;
  const int m0 = blockIdx.y * 64;
  const int n0 = blockIdx.x * 32;
  const int wm = wave & 1, wn = wave >> 1;
  float4v acc[2];
  acc[0] = (float4v){0.f, 0.f, 0.f, 0.f};
  acc[1] = (float4v){0.f, 0.f, 0.f, 0.f};
  short8 pa;
  float4 pf0, pf1;
  auto ldu = [&](int k0) {
    {
      int row = tid >> 2, q = tid & 3;
      pa = *(const short8*)(soutb + (size_t)(m0 + row) * DM + k0 + q * 8);
    }
    if (tid < 128) {
      int row = tid >> 2, q = tid & 3;
      const float4* p = (const float4*)(Wout + (size_t)(n0 + row) * DM + k0 + q * 8);
      pf0 = p[0]; pf1 = p[1];
    }
  };
  auto stu = [&]() {
    { int row = tid >> 2, q = tid & 3; *(short8*)&As[row * 40 + q * 8] = pa; }
    if (tid < 128) { int row = tid >> 2, q = tid & 3; *(short8*)&Bs[row * 40 + q * 8] = pack8(pf0, pf1); }
  };
  ldu(0);
  for (int k0 = 0; k0 < DM; k0 += 32) {
    stu();
    __syncthreads();
    if (k0 + 32 < DM) ldu(k0 + 32);
    short8 afr[2], bfr;
    afr[0] = *(const short8*)&As[(wm * 32 + r16) * 40 + quad * 8];
    afr[1] = *(const short8*)&As[(wm * 32 + 16 + r16) * 40 + quad * 8];
    bfr    = *(const short8*)&Bs[(wn * 16 + r16) * 40 + quad * 8];
    acc[0] = __builtin_amdgcn_mfma_f32_16x16x32_bf16(afr[0], bfr, acc[0], 0, 0, 0);
    acc[1] = __builtin_amdgcn_mfma_f32_16x16x32_bf16(afr[1], bfr, acc[1], 0, 0, 0);
    __syncthreads();
  }
#pragma unroll
  for (int mi = 0; mi < 2; mi++)
#pragma unroll
    for (int r = 0; r < 4; r++)
      out[(size_t)(m0 + wm * 32 + mi * 16 + quad * 4 + r) * DIN + n0 + wn * 16 + r16] = acc[mi][r];
}

// ---------------------------------------------------------------------------
extern "C" void kernel_launch(void* const* d_in, const int* in_sizes, int n_in,
                              void* d_out, int out_size, void* d_ws, size_t ws_size,
                              hipStream_t stream) {
  const float* seq  = (const float*)d_in[0];
  const float* Win  = (const float*)d_in[1];
  const float* Wout = (const float*)d_in[2];
  const float* WB   = (const float*)d_in[3];
  const float* WC   = (const float*)d_in[4];
  const float* WD1  = (const float*)d_in[5];
  const float* WD2  = (const float*)d_in[6];
  const float* cw   = (const float*)d_in[7];
  const float* cb   = (const float*)d_in[8];
  const float* A    = (const float*)d_in[9];
  const float* Dv   = (const float*)d_in[10];
  float* out = (float*)d_out;

  float* ws = (float*)d_ws;
  __hip_bfloat16* ab = (__hip_bfloat16*)ws;       // 2048*2048 bf16
  float* xt   = ws   + 2097152;                   // 1024*2048 f32  (x transposed)
  short* gt   = (short*)(xt + 2097152);           // 1024*2048 bf16 (gate transposed)
  float* dltT = (float*)(gt + 2097152);           // 1024*2048 f32  (delta transposed)
  float* pall = dltT + 2097152;                   // 2048*96 f32 (Bm|Cm|t1)
  short* soutb = (short*)(pall + 196608);         // 2048*1024 bf16
  // total ~35 MB (proven budget 47)
  float* t1   = pall + 32;                        // t1 rows at col 32 (ld 96)

  gemm1_k<<<dim3(16, 16), 512, 0, stream>>>(seq, Win, ab, pall);
  convproj_k<<<1280, 256, 0, stream>>>(ab, cw, cb, WB, WC, WD1, xt, gt, pall);
  delta_k<<<dim3(16, 32), 256, 0, stream>>>(t1, WD2, Dv, dltT);
  scan_fused_k<<<B_ * (DM / SD), 512, 0, stream>>>(xt, dltT, pall, A, Dv, gt, soutb);
  gemm2_k<<<dim3(16, 32), 256, 0, stream>>>(soutb, Wout, out);
}